// Round 1
// 9229.407 us; speedup vs baseline: 3.1943x; 3.1943x over previous
//
#include <hip/hip_runtime.h>

// ---------------- problem constants ----------------
#define B_    32
#define NTOK  197
#define E_    768
#define NH_   12
#define M_    3072
#define L_    12
#define NPAT  196
#define BN    (B_*NTOK)    // 6304
#define BNP   (B_*NPAT)    // 6272

typedef unsigned short bf16_t;
typedef short v8s __attribute__((ext_vector_type(8)));     // 8 bf16 = 4 VGPR MFMA frag
typedef float v4f __attribute__((ext_vector_type(4)));     // MFMA accumulator
typedef unsigned short u16x8 __attribute__((ext_vector_type(8)));

// ---------------- helpers ----------------
__device__ inline float bf2f(bf16_t u){
    union { unsigned int i; float f; } c; c.i = ((unsigned int)u) << 16; return c.f;
}
__device__ inline bf16_t f2bf(float f){
    union { float f; unsigned int i; } c; c.f = f;
    unsigned int u = c.i;
    u += 0x7FFFu + ((u >> 16) & 1u);   // round-to-nearest-even
    return (bf16_t)(u >> 16);
}
__device__ inline float lo16f(unsigned int u){
    union { unsigned int i; float f; } c; c.i = u << 16; return c.f;
}
__device__ inline float hi16f(unsigned int u){
    union { unsigned int i; float f; } c; c.i = u & 0xFFFF0000u; return c.f;
}
__device__ inline float wave_rsum(float x){
    #pragma unroll
    for (int off = 32; off; off >>= 1) x += __shfl_xor(x, off);
    return x;
}
__device__ inline float wave_rmax(float x){
    #pragma unroll
    for (int off = 32; off; off >>= 1) x = fmaxf(x, __shfl_xor(x, off));
    return x;
}

// ---------------- dtype detector ----------------
__global__ __launch_bounds__(256) void detect_k(const unsigned short* __restrict__ x,
                                                int n, int* __restrict__ flag){
    int cnt = 0;
    for (int i = blockIdx.x*256 + threadIdx.x; i < n; i += 256*64)
        { unsigned short u = x[i]; if (((u >> 7) & 0xFFu) == 0xFFu) ++cnt; }
    if (cnt) atomicAdd(flag, cnt);
}

// ---------------- canonicalize to bf16 ----------------
__global__ __launch_bounds__(256) void convert_k(const void* __restrict__ src,
    bf16_t* __restrict__ dst, int n, const int* __restrict__ flag){
    int i = blockIdx.x*256 + threadIdx.x;
    if (i >= n) return;
    if (*flag >= 8) dst[i] = f2bf(((const float*)src)[i]);
    else            dst[i] = ((const bf16_t*)src)[i];
}

// ---------------- transpose-canonicalize: src [L][K][N] -> dst [L][N][K] bf16 ----------------
// grid (N/32, K/32, L), 256 threads
__global__ __launch_bounds__(256) void convert_t_k(const void* __restrict__ src,
    bf16_t* __restrict__ dst, int K, int N, const int* __restrict__ flag){
    __shared__ float tile[32][33];
    const int l  = blockIdx.z;
    const int n0 = blockIdx.x*32, k0 = blockIdx.y*32;
    const int c  = threadIdx.x & 31, r = threadIdx.x >> 5;   // 8 rows x 32 cols, 4 iters
    const bool isf = (*flag >= 8);
    const size_t ibase = (size_t)l*(size_t)K*N;
    #pragma unroll
    for (int i = 0; i < 4; ++i){
        int kk = k0 + r + i*8;
        float v;
        if (isf) v = ((const float*)src)[ibase + (size_t)kk*N + n0 + c];
        else     v = bf2f(((const bf16_t*)src)[ibase + (size_t)kk*N + n0 + c]);
        tile[r + i*8][c] = v;
    }
    __syncthreads();
    #pragma unroll
    for (int i = 0; i < 4; ++i){
        int nn = n0 + r + i*8;
        dst[ibase + (size_t)nn*K + k0 + c] = f2bf(tile[c][r + i*8]);
    }
}

// ---------------- old VALU GEMM (fallback path only) ----------------
template<int AT, int BT, int OT, int ACT>
__global__ __launch_bounds__(256) void gemm_ab(
    const void* __restrict__ A, const bf16_t* __restrict__ Bw,
    const bf16_t* __restrict__ bias, void* __restrict__ C,
    int Mr, int Nc, int K)
{
    __shared__ float As[16][72];
    __shared__ float Bs[16][72];
    const int tx = threadIdx.x, ty = threadIdx.y;
    const int t  = ty*16 + tx;
    const int m0 = blockIdx.y*64, n0 = blockIdx.x*64;
    float acc[4][4] = {};

    for (int k0 = 0; k0 < K; k0 += 16){
        {
            int mm = t >> 2, kk = (t & 3)*4;
            int row = m0 + mm;
            float f0=0.f,f1=0.f,f2=0.f,f3=0.f;
            if (row < Mr){
                if (AT == 0){
                    const float4 v4 = *(const float4*)((const float*)A + (size_t)row*K + k0 + kk);
                    f0=v4.x; f1=v4.y; f2=v4.z; f3=v4.w;
                } else {
                    const ushort4 u4 = *(const ushort4*)((const bf16_t*)A + (size_t)row*K + k0 + kk);
                    f0=bf2f(u4.x); f1=bf2f(u4.y); f2=bf2f(u4.z); f3=bf2f(u4.w);
                }
            }
            As[kk+0][mm]=f0; As[kk+1][mm]=f1; As[kk+2][mm]=f2; As[kk+3][mm]=f3;
        }
        if (BT){
            int nn = t >> 2, kk = (t & 3)*4;
            const ushort4 u4 = *(const ushort4*)(Bw + (size_t)(n0+nn)*K + k0 + kk);
            Bs[kk+0][nn]=bf2f(u4.x); Bs[kk+1][nn]=bf2f(u4.y);
            Bs[kk+2][nn]=bf2f(u4.z); Bs[kk+3][nn]=bf2f(u4.w);
        } else {
            int kk = t >> 4, nn = (t & 15)*4;
            const ushort4 u4 = *(const ushort4*)(Bw + (size_t)(k0+kk)*Nc + n0 + nn);
            Bs[kk][nn+0]=bf2f(u4.x); Bs[kk][nn+1]=bf2f(u4.y);
            Bs[kk][nn+2]=bf2f(u4.z); Bs[kk][nn+3]=bf2f(u4.w);
        }
        __syncthreads();
        #pragma unroll
        for (int kk = 0; kk < 16; ++kk){
            float4 av = *(const float4*)&As[kk][ty*4];
            float4 bv = *(const float4*)&Bs[kk][tx*4];
            float a_[4] = {av.x, av.y, av.z, av.w};
            float b_[4] = {bv.x, bv.y, bv.z, bv.w};
            #pragma unroll
            for (int i=0;i<4;i++)
                #pragma unroll
                for (int j=0;j<4;j++)
                    acc[i][j] += a_[i]*b_[j];
        }
        __syncthreads();
    }
    #pragma unroll
    for (int i=0;i<4;i++){
        int m = m0 + ty*4 + i;
        if (m >= Mr) continue;
        #pragma unroll
        for (int j=0;j<4;j++){
            int n = n0 + tx*4 + j;
            float v = acc[i][j];
            if (bias) v += bf2f(bias[n]);
            if (ACT==1) v = 0.5f*v*(1.f + erff(v*0.70710678118654752f));
            if (OT == 0) ((float*)C)[(size_t)m*Nc + n] = v;
            else         ((bf16_t*)C)[(size_t)m*Nc + n] = f2bf(v);
        }
    }
}

// ---------------- MFMA bf16 GEMM: C[M,N] = A @ Bt^T (+bias, opt GELU) ----------------
// A: [Mr][K] bf16 row-major; Bt: [Nc][K] bf16 row-major (i.e. B transposed).
// tile 128x128, BK=32, 256 threads = 4 waves (2x2), each wave 64x64 (4x4 frags 16x16).
// Fragment layout (m92/m97-verified): A-frag lane l = A[l&15][8*(l>>4)+e] (8 contiguous k);
// B-frag lane l = B[8*(l>>4)+e][l&15]; C/D: col=l&15, row=4*(l>>4)+reg.
// Requires K%32==0, Nc%128==0; M-edge clamped+guarded.
template<int OT, int ACT>
__global__ __launch_bounds__(256) void gemm_mfma(
    const bf16_t* __restrict__ A, const bf16_t* __restrict__ Bt,
    const bf16_t* __restrict__ bias, void* __restrict__ C,
    int Mr, int Nc, int K)
{
    __shared__ __align__(16) char As[128*32*2];
    __shared__ __align__(16) char Bs[128*32*2];
    const int t    = threadIdx.x;
    const int lane = t & 63;
    const int wave = t >> 6;
    const int wr = wave >> 1, wc = wave & 1;
    const int m0 = blockIdx.y * 128, n0 = blockIdx.x * 128;

    // staging: thread covers (row = t>>1, k-half = t&1 -> 16 elems = 2x16B)
    const int srow = t >> 1, shalf = t & 1;
    int arow = m0 + srow; if (arow >= Mr) arow = Mr - 1;   // clamp; junk rows never stored
    const bf16_t* ag = A  + (size_t)arow * K + shalf * 16;
    const bf16_t* bg = Bt + (size_t)(n0 + srow) * K + shalf * 16;
    const int wbase = srow*64 + shalf*32;          // tile byte offset of this thread's chunk
    const int wswz  = (srow & 7) << 4;             // XOR swizzle (bank-conflict fix)
    const int w0 = (wbase)      ^ wswz;
    const int w1 = (wbase + 16) ^ wswz;

    // fragment read offsets
    const int fr = lane & 15, fg = lane >> 4;
    int aoff[4], boff[4];
    #pragma unroll
    for (int s = 0; s < 4; ++s){
        int ar = wr*64 + s*16 + fr;                // tile row for A frag
        int br = wc*64 + s*16 + fr;                // tile row (=output col) for B frag
        aoff[s] = (ar*64 + fg*16) ^ ((ar & 7) << 4);
        boff[s] = (br*64 + fg*16) ^ ((br & 7) << 4);
    }

    const v4f vzero = {0.f, 0.f, 0.f, 0.f};
    v4f acc[4][4];
    #pragma unroll
    for (int i = 0; i < 4; ++i)
        #pragma unroll
        for (int j = 0; j < 4; ++j)
            acc[i][j] = vzero;

    for (int k0 = 0; k0 < K; k0 += 32){
        u16x8 a0 = *(const u16x8*)(ag + k0);
        u16x8 a1 = *(const u16x8*)(ag + k0 + 8);
        u16x8 b0 = *(const u16x8*)(bg + k0);
        u16x8 b1 = *(const u16x8*)(bg + k0 + 8);
        __syncthreads();                  // previous iteration's reads done
        *(u16x8*)(As + w0) = a0;
        *(u16x8*)(As + w1) = a1;
        *(u16x8*)(Bs + w0) = b0;
        *(u16x8*)(Bs + w1) = b1;
        __syncthreads();                  // tile staged
        v8s af[4], bfv[4];
        #pragma unroll
        for (int s = 0; s < 4; ++s){
            af[s]  = *(const v8s*)(As + aoff[s]);
            bfv[s] = *(const v8s*)(Bs + boff[s]);
        }
        #pragma unroll
        for (int i = 0; i < 4; ++i)
            #pragma unroll
            for (int j = 0; j < 4; ++j)
                acc[i][j] = __builtin_amdgcn_mfma_f32_16x16x32_bf16(af[i], bfv[j], acc[i][j], 0, 0, 0);
    }

    // epilogue: C row = 4*(l>>4)+r, col = l&15 within each 16x16 frag
    #pragma unroll
    for (int i = 0; i < 4; ++i){
        #pragma unroll
        for (int r = 0; r < 4; ++r){
            int m = m0 + wr*64 + i*16 + fg*4 + r;
            if (m >= Mr) continue;
            #pragma unroll
            for (int j = 0; j < 4; ++j){
                int n = n0 + wc*64 + j*16 + fr;
                float v = acc[i][j][r];
                if (bias) v += bf2f(bias[n]);
                if (ACT == 1) v = 0.5f*v*(1.f + erff(v*0.70710678118654752f));
                if (OT == 0) ((float*)C)[(size_t)m*Nc + n] = v;
                else         ((bf16_t*)C)[(size_t)m*Nc + n] = f2bf(v);
            }
        }
    }
}

// ---------------- patchify (fallback, f32 out) ----------------
__global__ __launch_bounds__(256) void patchify_k(const bf16_t* __restrict__ x, float* __restrict__ out){
    int idx = blockIdx.x*256 + threadIdx.x;
    if (idx >= BNP*E_) return;
    int kk  = idx % 768;
    int bnp = idx / 768;
    int b = bnp / 196, np = bnp % 196;
    int ph = np / 14,  pw = np % 14;
    int c = kk >> 8, rr = kk & 255;
    int i = rr >> 4, j = rr & 15;
    size_t xi = (((size_t)(b*3 + c))*224 + (ph*16 + i))*224 + (pw*16 + j);
    out[idx] = bf2f(x[xi]);
}

// ---------------- patchify bf16 out (hedge path; pure copy) ----------------
__global__ __launch_bounds__(256) void patchify_bf_k(const bf16_t* __restrict__ x, bf16_t* __restrict__ out){
    int idx = blockIdx.x*256 + threadIdx.x;
    if (idx >= BNP*E_) return;
    int kk  = idx % 768;
    int bnp = idx / 768;
    int b = bnp / 196, np = bnp % 196;
    int ph = np / 14,  pw = np % 14;
    int c = kk >> 8, rr = kk & 255;
    int i = rr >> 4, j = rr & 15;
    size_t xi = (((size_t)(b*3 + c))*224 + (ph*16 + i))*224 + (pw*16 + j);
    out[idx] = x[xi];
}

// ---------------- assemble h = [cls | patch_emb] + pos, plus bf16 copy ----------------
__global__ __launch_bounds__(256) void assemble_k(const float* __restrict__ pe,
    const bf16_t* __restrict__ cls, const bf16_t* __restrict__ pos,
    float* __restrict__ h, bf16_t* __restrict__ hb){
    int idx = blockIdx.x*256 + threadIdx.x;
    if (idx >= BN*E_) return;
    int e = idx % 768; int bn = idx / 768;
    int b = bn / 197,  n  = bn % 197;
    float v = (n == 0) ? bf2f(cls[e]) : pe[((size_t)b*196 + (n-1))*768 + e];
    float r = v + bf2f(pos[n*768 + e]);
    h[idx]  = r;
    hb[idx] = f2bf(r);
}

// ---------------- qkv split + q/k LayerNorm (D=64); q scaled by 1/8 ----------------
__global__ __launch_bounds__(256) void qkv_split_ln_k(const bf16_t* __restrict__ qkv,
    const bf16_t* __restrict__ qg, const bf16_t* __restrict__ qb,
    const bf16_t* __restrict__ kg, const bf16_t* __restrict__ kb,
    bf16_t* __restrict__ q, bf16_t* __restrict__ k, bf16_t* __restrict__ v){
    int lane = threadIdx.x & 63;
    int item = blockIdx.x*4 + (threadIdx.x >> 6);
    if (item >= BN*NH_) return;
    int bn = item / NH_, h = item % NH_;
    int b = bn / 197,   n = bn % 197;
    size_t src = (size_t)bn*2304 + h*64 + lane;
    size_t dst = (((size_t)(b*NH_ + h))*197 + n)*64 + lane;
    {
        float xv = bf2f(qkv[src]);
        float mu  = wave_rsum(xv) * (1.f/64.f);
        float dd  = xv - mu;
        float var = wave_rsum(dd*dd) * (1.f/64.f);
        q[dst] = f2bf((dd * rsqrtf(var + 1e-5f) * bf2f(qg[lane]) + bf2f(qb[lane])) * 0.125f);
    }
    {
        float xv = bf2f(qkv[src + 768]);
        float mu  = wave_rsum(xv) * (1.f/64.f);
        float dd  = xv - mu;
        float var = wave_rsum(dd*dd) * (1.f/64.f);
        k[dst] = f2bf(dd * rsqrtf(var + 1e-5f) * bf2f(kg[lane]) + bf2f(kb[lane]));
    }
    v[dst] = qkv[src + 1536];
}

// ---------------- attention: block = (b,h) x 16 query rows; lane-parallel scores ----------------
// K^T pair-packed over d: ktp[d/2][m]; V^T pair-packed over m: vtp[d][m/2].
// Each wave: 4 query rows; lane owns score cols m = lane + 64t. Output bf16.
__global__ __launch_bounds__(256) void attn_blk_k(const bf16_t* __restrict__ qn,
    const bf16_t* __restrict__ kn, const bf16_t* __restrict__ vn, bf16_t* __restrict__ o){
    __shared__ unsigned int ktp[32][203];   // lo=K[m][2d2], hi=K[m][2d2+1]
    __shared__ unsigned int vtp[64][105];   // lo=V[2m2][d], hi=V[2m2+1][d]
    __shared__ float qly[4][64];
    __shared__ float ply[4][256];
    const int lane = threadIdx.x & 63, wave = threadIdx.x >> 6;
    const int bh = blockIdx.y;
    const int b = bh / NH_, h = bh % NH_;
    const bf16_t* kb = kn + (size_t)bh*197*64;
    const bf16_t* vb = vn + (size_t)bh*197*64;

    // stage K^T / V^T (zero-padded past m=196)
    for (int m = wave; m < 210; m += 4){
        bf16_t kv = 0, vv = 0;
        if (m < 197){ kv = kb[(size_t)m*64 + lane]; vv = vb[(size_t)m*64 + lane]; }
        if (m < 203)
            ((bf16_t*)ktp)[((size_t)(lane >> 1)*203 + m)*2 + (lane & 1)] = kv;
        ((bf16_t*)vtp)[((size_t)lane*105 + (m >> 1))*2 + (m & 1)] = vv;
    }
    __syncthreads();

    const int n0 = blockIdx.x*16 + wave*4;
    for (int i = 0; i < 4; ++i){
        int n = n0 + i;
        int nn = (n < 197) ? n : 196;
        qly[wave][lane] = bf2f(qn[((size_t)bh*197 + nn)*64 + lane]);   // wave-local, in-order LDS
        float s0 = 0.f, s1 = 0.f, s2 = 0.f, s3 = 0.f;
        const int m3 = (lane < 5) ? lane + 192 : 196;   // clamped; masked below
        #pragma unroll 8
        for (int d2 = 0; d2 < 32; ++d2){
            float2 q2 = *(const float2*)&qly[wave][2*d2];
            unsigned int k0 = ktp[d2][lane];
            unsigned int k1 = ktp[d2][lane + 64];
            unsigned int k2 = ktp[d2][lane + 128];
            unsigned int k3 = ktp[d2][m3];
            s0 += q2.x * lo16f(k0) + q2.y * hi16f(k0);
            s1 += q2.x * lo16f(k1) + q2.y * hi16f(k1);
            s2 += q2.x * lo16f(k2) + q2.y * hi16f(k2);
            s3 += q2.x * lo16f(k3) + q2.y * hi16f(k3);
        }
        if (lane >= 5) s3 = -1e30f;
        float mx = wave_rmax(fmaxf(fmaxf(s0, s1), fmaxf(s2, s3)));
        float p0 = expf(s0 - mx), p1 = expf(s1 - mx), p2 = expf(s2 - mx);
        float p3 = (lane < 5) ? expf(s3 - mx) : 0.f;
        float sum = wave_rsum(p0 + p1 + p2 + p3);
        float inv = 1.f / sum;
        ply[wave][lane      ] = p0*inv;
        ply[wave][lane +  64] = p1*inv;
        ply[wave][lane + 128] = p2*inv;
        ply[wave][lane + 192] = p3*inv;   // zeros for m>=197
        float acc = 0.f;
        #pragma unroll 4
        for (int m2 = 0; m2 < 99; ++m2){
            float2 p2v = *(const float2*)&ply[wave][2*m2];
            unsigned int vv = vtp[lane][m2];
            acc += p2v.x * lo16f(vv) + p2v.y * hi16f(vv);
        }
        if (n < 197) o[((size_t)(b*197 + n))*768 + h*64 + lane] = f2bf(acc);
    }
}

// ---------------- h[row] += LN(src[row])*g + b ; also writes bf16 copy of h ----------------
__global__ __launch_bounds__(256) void lnadd_k(const float* __restrict__ src,
    const bf16_t* __restrict__ g, const bf16_t* __restrict__ b,
    float* __restrict__ h, bf16_t* __restrict__ hb){
    __shared__ float red[256];
    int t = threadIdx.x;
    size_t row = blockIdx.x;
    const float* p = src + row*768;
    float x0 = p[t], x1 = p[t+256], x2 = p[t+512];
    red[t] = x0 + x1 + x2;
    __syncthreads();
    for (int off = 128; off; off >>= 1){ if (t < off) red[t] += red[t+off]; __syncthreads(); }
    float mean = red[0] * (1.f/768.f);
    __syncthreads();
    float d0 = x0-mean, d1 = x1-mean, d2 = x2-mean;
    red[t] = d0*d0 + d1*d1 + d2*d2;
    __syncthreads();
    for (int off = 128; off; off >>= 1){ if (t < off) red[t] += red[t+off]; __syncthreads(); }
    float inv = rsqrtf(red[0]*(1.f/768.f) + 1e-5f);
    float* hp = h + row*768;
    bf16_t* hq = hb + row*768;
    float r0 = hp[t]     + d0*inv*bf2f(g[t])     + bf2f(b[t]);
    float r1 = hp[t+256] + d1*inv*bf2f(g[t+256]) + bf2f(b[t+256]);
    float r2 = hp[t+512] + d2*inv*bf2f(g[t+512]) + bf2f(b[t+512]);
    hp[t] = r0;     hq[t] = f2bf(r0);
    hp[t+256] = r1; hq[t+256] = f2bf(r1);
    hp[t+512] = r2; hq[t+512] = f2bf(r2);
}

// ---------------- output: h[:,0,:] -> f32 ----------------
__global__ __launch_bounds__(256) void outcopy_k(const float* __restrict__ h, float* __restrict__ out){
    int idx = blockIdx.x*256 + threadIdx.x;
    if (idx >= B_*E_) return;
    int b = idx / 768, e = idx % 768;
    out[idx] = h[(size_t)b*197*768 + e];
}

// ---------------- workspace layout (bytes) ----------------
// [0, 19365888)              h    f32 [6304,768]
// [19365888, 38731776)       t1   f32 [6304,768]  (also attn-out bf16 alias)
// [38731776, ...)            R region (lifetime-overlapped):
//    qkvbuf bf16 [6304,2304] @ R+0 ; patches bf16 @ R+0 ; projout f32 @ R+0
//    fbuf bf16 [6304,3072]   @ R+0  (overlaps dead qn/kn)
//    qn @ R+29048832, kn @ +9682944, vn/habf @ +9682944 (disjoint lifetimes)
// total = 96,829,440 ; flag @ 96,829,440 ; canonical copies @ 96,829,696
#define OFF_T1   ((size_t)19365888)
#define OFF_R    ((size_t)38731776)
#define OFF_QN   ((size_t)(38731776 + 29048832))        // 67,780,608
#define OFF_KN   ((size_t)(67780608 + 9682944))         // 77,463,552
#define OFF_VN   ((size_t)(77463552 + 9682944))         // 87,146,496
#define OFF_FLAG ((size_t)96829440)
#define OFF_CONV ((size_t)96829696)

extern "C" void kernel_launch(void* const* d_in, const int* in_sizes, int n_in,
                              void* d_out, int out_size, void* d_ws, size_t ws_size,
                              hipStream_t stream) {
    (void)out_size;
    char* wsb = (char*)d_ws;
    float*  h       = (float*)(wsb);
    float*  t1      = (float*)(wsb + OFF_T1);
    bf16_t* abf     = (bf16_t*)(wsb + OFF_T1);          // attn out bf16 (aliases t1)
    bf16_t* qkvbuf  = (bf16_t*)(wsb + OFF_R);
    bf16_t* patches = (bf16_t*)(wsb + OFF_R);
    float*  patchf  = (float*)(wsb + OFF_R);
    float*  projout = (float*)(wsb + OFF_R);
    bf16_t* fbuf    = (bf16_t*)(wsb + OFF_R);
    bf16_t* qnb     = (bf16_t*)(wsb + OFF_QN);
    bf16_t* knb     = (bf16_t*)(wsb + OFF_KN);
    bf16_t* vnb     = (bf16_t*)(wsb + OFF_VN);
    bf16_t* habf    = (bf16_t*)(wsb + OFF_VN);          // h bf16 copy (disjoint lifetime vs vn)
    int*    flag    = (int*)(wsb + OFF_FLAG);

    size_t conv_total = 0;
    for (int i = 0; i < n_in; ++i) conv_total += (((size_t)in_sizes[i]*2) + 15) & ~(size_t)15;
    const bool hedge = (ws_size >= OFF_CONV + conv_total);

    const bf16_t* inp[21];
    if (hedge){
        hipMemsetAsync(flag, 0, 4, stream);
        detect_k<<<64, 256, 0, stream>>>((const unsigned short*)d_in[0], in_sizes[0], flag);
        size_t off = 0;
        for (int i = 0; i < n_in && i < 21; ++i){
            bf16_t* dst = (bf16_t*)(wsb + OFF_CONV + off);
            if (i == 5)       // qkv_w [12][768][2304] -> [12][2304][768]
                convert_t_k<<<dim3(2304/32, 768/32, 12), 256, 0, stream>>>(d_in[i], dst, 768, 2304, flag);
            else if (i == 11) // proj_w [12][768][768] -> transposed
                convert_t_k<<<dim3(768/32, 768/32, 12), 256, 0, stream>>>(d_in[i], dst, 768, 768, flag);
            else if (i == 15) // w1 [12][768][3072] -> [12][3072][768]
                convert_t_k<<<dim3(3072/32, 768/32, 12), 256, 0, stream>>>(d_in[i], dst, 768, 3072, flag);
            else if (i == 17) // w2 [12][3072][768] -> [12][768][3072]
                convert_t_k<<<dim3(768/32, 3072/32, 12), 256, 0, stream>>>(d_in[i], dst, 3072, 768, flag);
            else
                convert_k<<<(in_sizes[i] + 255)/256, 256, 0, stream>>>(d_in[i], dst, in_sizes[i], flag);
            inp[i] = dst;
            off += (((size_t)in_sizes[i]*2) + 15) & ~(size_t)15;
        }
    } else {
        for (int i = 0; i < n_in && i < 21; ++i) inp[i] = (const bf16_t*)d_in[i];
    }

    if (hedge){
        // ---- MFMA pipeline ----
        patchify_bf_k<<<(BNP*E_ + 255)/256, 256, 0, stream>>>(inp[0], patches);
        gemm_mfma<0,0><<<dim3(E_/128, BNP/128), 256, 0, stream>>>(
            patches, inp[1], inp[2], t1, BNP, E_, 768);
        assemble_k<<<(BN*E_ + 255)/256, 256, 0, stream>>>(t1, inp[3], inp[4], h, habf);

        for (int l = 0; l < L_; ++l){
            gemm_mfma<1,0><<<dim3(2304/128, (BN+127)/128), 256, 0, stream>>>(
                habf, inp[5] + (size_t)l*E_*2304, inp[6] + (size_t)l*2304, qkvbuf, BN, 2304, 768);
            qkv_split_ln_k<<<(BN*NH_)/4, 256, 0, stream>>>(
                qkvbuf, inp[7] + l*64, inp[8] + l*64, inp[9] + l*64, inp[10] + l*64,
                qnb, knb, vnb);
            attn_blk_k<<<dim3(13, B_*NH_), 256, 0, stream>>>(qnb, knb, vnb, abf);
            gemm_mfma<0,0><<<dim3(E_/128, (BN+127)/128), 256, 0, stream>>>(
                abf, inp[11] + (size_t)l*E_*E_, inp[12] + (size_t)l*E_, projout, BN, E_, 768);
            lnadd_k<<<BN, 256, 0, stream>>>(projout, inp[13] + l*E_, inp[14] + l*E_, h, habf);
            gemm_mfma<1,1><<<dim3(M_/128, (BN+127)/128), 256, 0, stream>>>(
                habf, inp[15] + (size_t)l*E_*M_, inp[16] + (size_t)l*M_, fbuf, BN, M_, 768);
            gemm_mfma<0,0><<<dim3(E_/128, (BN+127)/128), 256, 0, stream>>>(
                fbuf, inp[17] + (size_t)l*M_*E_, inp[18] + (size_t)l*E_, t1, BN, E_, 3072);
            lnadd_k<<<BN, 256, 0, stream>>>(t1, inp[19] + l*E_, inp[20] + l*E_, h, habf);
        }
    } else {
        // ---- fallback VALU pipeline (inputs assumed bf16 in place) ----
        dim3 gblk(16, 16);
        patchify_k<<<(BNP*E_ + 255)/256, 256, 0, stream>>>(inp[0], patchf);
        gemm_ab<0,1,0,0><<<dim3(E_/64, BNP/64), gblk, 0, stream>>>(
            patchf, inp[1], inp[2], t1, BNP, E_, 768);
        assemble_k<<<(BN*E_ + 255)/256, 256, 0, stream>>>(t1, inp[3], inp[4], h, habf);
        for (int l = 0; l < L_; ++l){
            gemm_ab<0,0,1,0><<<dim3(2304/64, (BN+63)/64), gblk, 0, stream>>>(
                h, inp[5] + (size_t)l*E_*2304, inp[6] + (size_t)l*2304, qkvbuf, BN, 2304, E_);
            qkv_split_ln_k<<<(BN*NH_)/4, 256, 0, stream>>>(
                qkvbuf, inp[7] + l*64, inp[8] + l*64, inp[9] + l*64, inp[10] + l*64,
                qnb, knb, vnb);
            attn_blk_k<<<dim3(13, B_*NH_), 256, 0, stream>>>(qnb, knb, vnb, abf);
            gemm_ab<1,0,0,0><<<dim3(E_/64, (BN+63)/64), gblk, 0, stream>>>(
                abf, inp[11] + (size_t)l*E_*E_, inp[12] + (size_t)l*E_, projout, BN, E_, E_);
            lnadd_k<<<BN, 256, 0, stream>>>(projout, inp[13] + l*E_, inp[14] + l*E_, h, habf);
            gemm_ab<0,0,1,1><<<dim3(M_/64, (BN+63)/64), gblk, 0, stream>>>(
                h, inp[15] + (size_t)l*E_*M_, inp[16] + (size_t)l*M_, fbuf, BN, M_, E_);
            gemm_ab<1,0,0,0><<<dim3(E_/64, (BN+63)/64), gblk, 0, stream>>>(
                fbuf, inp[17] + (size_t)l*M_*E_, inp[18] + (size_t)l*E_, t1, BN, E_, M_);
            lnadd_k<<<BN, 256, 0, stream>>>(t1, inp[19] + l*E_, inp[20] + l*E_, h, habf);
        }
    }

    outcopy_k<<<(B_*E_ + 255)/256, 256, 0, stream>>>(h, (float*)d_out);
}

// Round 2
// 5177.837 us; speedup vs baseline: 5.6937x; 1.7825x over previous
//
#include <hip/hip_runtime.h>

// ---------------- problem constants ----------------
#define B_    32
#define NTOK  197
#define E_    768
#define NH_   12
#define M_    3072
#define L_    12
#define NPAT  196
#define BN    (B_*NTOK)    // 6304
#define BNP   (B_*NPAT)    // 6272

typedef unsigned short bf16_t;
typedef short v8s __attribute__((ext_vector_type(8)));     // 8 bf16 = 4 VGPR MFMA frag
typedef float v4f __attribute__((ext_vector_type(4)));     // MFMA accumulator
typedef unsigned short u16x8 __attribute__((ext_vector_type(8)));

// ---------------- helpers ----------------
__device__ inline float bf2f(bf16_t u){
    union { unsigned int i; float f; } c; c.i = ((unsigned int)u) << 16; return c.f;
}
__device__ inline bf16_t f2bf(float f){
    union { float f; unsigned int i; } c; c.f = f;
    unsigned int u = c.i;
    u += 0x7FFFu + ((u >> 16) & 1u);   // round-to-nearest-even
    return (bf16_t)(u >> 16);
}
__device__ inline float lo16f(unsigned int u){
    union { unsigned int i; float f; } c; c.i = u << 16; return c.f;
}
__device__ inline float hi16f(unsigned int u){
    union { unsigned int i; float f; } c; c.i = u & 0xFFFF0000u; return c.f;
}
__device__ inline float wave_rsum(float x){
    #pragma unroll
    for (int off = 32; off; off >>= 1) x += __shfl_xor(x, off);
    return x;
}
__device__ inline float wave_rmax(float x){
    #pragma unroll
    for (int off = 32; off; off >>= 1) x = fmaxf(x, __shfl_xor(x, off));
    return x;
}

// ---------------- dtype detector ----------------
__global__ __launch_bounds__(256) void detect_k(const unsigned short* __restrict__ x,
                                                int n, int* __restrict__ flag){
    int cnt = 0;
    for (int i = blockIdx.x*256 + threadIdx.x; i < n; i += 256*64)
        { unsigned short u = x[i]; if (((u >> 7) & 0xFFu) == 0xFFu) ++cnt; }
    if (cnt) atomicAdd(flag, cnt);
}

// ---------------- canonicalize to bf16 ----------------
__global__ __launch_bounds__(256) void convert_k(const void* __restrict__ src,
    bf16_t* __restrict__ dst, int n, const int* __restrict__ flag){
    int i = blockIdx.x*256 + threadIdx.x;
    if (i >= n) return;
    if (*flag >= 8) dst[i] = f2bf(((const float*)src)[i]);
    else            dst[i] = ((const bf16_t*)src)[i];
}

// ---------------- transpose-canonicalize: src [L][K][N] -> dst [L][N][K] bf16 ----------------
__global__ __launch_bounds__(256) void convert_t_k(const void* __restrict__ src,
    bf16_t* __restrict__ dst, int K, int N, const int* __restrict__ flag){
    __shared__ float tile[32][33];
    const int l  = blockIdx.z;
    const int n0 = blockIdx.x*32, k0 = blockIdx.y*32;
    const int c  = threadIdx.x & 31, r = threadIdx.x >> 5;
    const bool isf = (*flag >= 8);
    const size_t ibase = (size_t)l*(size_t)K*N;
    #pragma unroll
    for (int i = 0; i < 4; ++i){
        int kk = k0 + r + i*8;
        float v;
        if (isf) v = ((const float*)src)[ibase + (size_t)kk*N + n0 + c];
        else     v = bf2f(((const bf16_t*)src)[ibase + (size_t)kk*N + n0 + c]);
        tile[r + i*8][c] = v;
    }
    __syncthreads();
    #pragma unroll
    for (int i = 0; i < 4; ++i){
        int nn = n0 + r + i*8;
        dst[ibase + (size_t)nn*K + k0 + c] = f2bf(tile[c][r + i*8]);
    }
}

// ---------------- old VALU GEMM (fallback path only) ----------------
template<int AT, int BT, int OT, int ACT>
__global__ __launch_bounds__(256) void gemm_ab(
    const void* __restrict__ A, const bf16_t* __restrict__ Bw,
    const bf16_t* __restrict__ bias, void* __restrict__ C,
    int Mr, int Nc, int K)
{
    __shared__ float As[16][72];
    __shared__ float Bs[16][72];
    const int tx = threadIdx.x, ty = threadIdx.y;
    const int t  = ty*16 + tx;
    const int m0 = blockIdx.y*64, n0 = blockIdx.x*64;
    float acc[4][4] = {};

    for (int k0 = 0; k0 < K; k0 += 16){
        {
            int mm = t >> 2, kk = (t & 3)*4;
            int row = m0 + mm;
            float f0=0.f,f1=0.f,f2=0.f,f3=0.f;
            if (row < Mr){
                if (AT == 0){
                    const float4 v4 = *(const float4*)((const float*)A + (size_t)row*K + k0 + kk);
                    f0=v4.x; f1=v4.y; f2=v4.z; f3=v4.w;
                } else {
                    const ushort4 u4 = *(const ushort4*)((const bf16_t*)A + (size_t)row*K + k0 + kk);
                    f0=bf2f(u4.x); f1=bf2f(u4.y); f2=bf2f(u4.z); f3=bf2f(u4.w);
                }
            }
            As[kk+0][mm]=f0; As[kk+1][mm]=f1; As[kk+2][mm]=f2; As[kk+3][mm]=f3;
        }
        if (BT){
            int nn = t >> 2, kk = (t & 3)*4;
            const ushort4 u4 = *(const ushort4*)(Bw + (size_t)(n0+nn)*K + k0 + kk);
            Bs[kk+0][nn]=bf2f(u4.x); Bs[kk+1][nn]=bf2f(u4.y);
            Bs[kk+2][nn]=bf2f(u4.z); Bs[kk+3][nn]=bf2f(u4.w);
        } else {
            int kk = t >> 4, nn = (t & 15)*4;
            const ushort4 u4 = *(const ushort4*)(Bw + (size_t)(k0+kk)*Nc + n0 + nn);
            Bs[kk][nn+0]=bf2f(u4.x); Bs[kk][nn+1]=bf2f(u4.y);
            Bs[kk][nn+2]=bf2f(u4.z); Bs[kk][nn+3]=bf2f(u4.w);
        }
        __syncthreads();
        #pragma unroll
        for (int kk = 0; kk < 16; ++kk){
            float4 av = *(const float4*)&As[kk][ty*4];
            float4 bv = *(const float4*)&Bs[kk][tx*4];
            float a_[4] = {av.x, av.y, av.z, av.w};
            float b_[4] = {bv.x, bv.y, bv.z, bv.w};
            #pragma unroll
            for (int i=0;i<4;i++)
                #pragma unroll
                for (int j=0;j<4;j++)
                    acc[i][j] += a_[i]*b_[j];
        }
        __syncthreads();
    }
    #pragma unroll
    for (int i=0;i<4;i++){
        int m = m0 + ty*4 + i;
        if (m >= Mr) continue;
        #pragma unroll
        for (int j=0;j<4;j++){
            int n = n0 + tx*4 + j;
            float v = acc[i][j];
            if (bias) v += bf2f(bias[n]);
            if (ACT==1) v = 0.5f*v*(1.f + erff(v*0.70710678118654752f));
            if (OT == 0) ((float*)C)[(size_t)m*Nc + n] = v;
            else         ((bf16_t*)C)[(size_t)m*Nc + n] = f2bf(v);
        }
    }
}

// ---------------- MFMA bf16 GEMM: C[M,N] = A @ Bt^T (+bias, opt GELU) ----------------
template<int OT, int ACT>
__global__ __launch_bounds__(256) void gemm_mfma(
    const bf16_t* __restrict__ A, const bf16_t* __restrict__ Bt,
    const bf16_t* __restrict__ bias, void* __restrict__ C,
    int Mr, int Nc, int K)
{
    __shared__ __align__(16) char As[128*32*2];
    __shared__ __align__(16) char Bs[128*32*2];
    const int t    = threadIdx.x;
    const int lane = t & 63;
    const int wave = t >> 6;
    const int wr = wave >> 1, wc = wave & 1;
    const int m0 = blockIdx.y * 128, n0 = blockIdx.x * 128;

    const int srow = t >> 1, shalf = t & 1;
    int arow = m0 + srow; if (arow >= Mr) arow = Mr - 1;
    const bf16_t* ag = A  + (size_t)arow * K + shalf * 16;
    const bf16_t* bg = Bt + (size_t)(n0 + srow) * K + shalf * 16;
    const int wbase = srow*64 + shalf*32;
    const int wswz  = (srow & 7) << 4;
    const int w0 = (wbase)      ^ wswz;
    const int w1 = (wbase + 16) ^ wswz;

    const int fr = lane & 15, fg = lane >> 4;
    int aoff[4], boff[4];
    #pragma unroll
    for (int s = 0; s < 4; ++s){
        int ar = wr*64 + s*16 + fr;
        int br = wc*64 + s*16 + fr;
        aoff[s] = (ar*64 + fg*16) ^ ((ar & 7) << 4);
        boff[s] = (br*64 + fg*16) ^ ((br & 7) << 4);
    }

    const v4f vzero = {0.f, 0.f, 0.f, 0.f};
    v4f acc[4][4];
    #pragma unroll
    for (int i = 0; i < 4; ++i)
        #pragma unroll
        for (int j = 0; j < 4; ++j)
            acc[i][j] = vzero;

    for (int k0 = 0; k0 < K; k0 += 32){
        u16x8 a0 = *(const u16x8*)(ag + k0);
        u16x8 a1 = *(const u16x8*)(ag + k0 + 8);
        u16x8 b0 = *(const u16x8*)(bg + k0);
        u16x8 b1 = *(const u16x8*)(bg + k0 + 8);
        __syncthreads();
        *(u16x8*)(As + w0) = a0;
        *(u16x8*)(As + w1) = a1;
        *(u16x8*)(Bs + w0) = b0;
        *(u16x8*)(Bs + w1) = b1;
        __syncthreads();
        v8s af[4], bfv[4];
        #pragma unroll
        for (int s = 0; s < 4; ++s){
            af[s]  = *(const v8s*)(As + aoff[s]);
            bfv[s] = *(const v8s*)(Bs + boff[s]);
        }
        #pragma unroll
        for (int i = 0; i < 4; ++i)
            #pragma unroll
            for (int j = 0; j < 4; ++j)
                acc[i][j] = __builtin_amdgcn_mfma_f32_16x16x32_bf16(af[i], bfv[j], acc[i][j], 0, 0, 0);
    }

    #pragma unroll
    for (int i = 0; i < 4; ++i){
        #pragma unroll
        for (int r = 0; r < 4; ++r){
            int m = m0 + wr*64 + i*16 + fg*4 + r;
            if (m >= Mr) continue;
            #pragma unroll
            for (int j = 0; j < 4; ++j){
                int n = n0 + wc*64 + j*16 + fr;
                float v = acc[i][j][r];
                if (bias) v += bf2f(bias[n]);
                if (ACT == 1) v = 0.5f*v*(1.f + erff(v*0.70710678118654752f));
                if (OT == 0) ((float*)C)[(size_t)m*Nc + n] = v;
                else         ((bf16_t*)C)[(size_t)m*Nc + n] = f2bf(v);
            }
        }
    }
}

// ---------------- patchify (fallback, f32 out) ----------------
__global__ __launch_bounds__(256) void patchify_k(const bf16_t* __restrict__ x, float* __restrict__ out){
    int idx = blockIdx.x*256 + threadIdx.x;
    if (idx >= BNP*E_) return;
    int kk  = idx % 768;
    int bnp = idx / 768;
    int b = bnp / 196, np = bnp % 196;
    int ph = np / 14,  pw = np % 14;
    int c = kk >> 8, rr = kk & 255;
    int i = rr >> 4, j = rr & 15;
    size_t xi = (((size_t)(b*3 + c))*224 + (ph*16 + i))*224 + (pw*16 + j);
    out[idx] = bf2f(x[xi]);
}

// ---------------- patchify bf16 out (hedge path) ----------------
__global__ __launch_bounds__(256) void patchify_bf_k(const bf16_t* __restrict__ x, bf16_t* __restrict__ out){
    int idx = blockIdx.x*256 + threadIdx.x;
    if (idx >= BNP*E_) return;
    int kk  = idx % 768;
    int bnp = idx / 768;
    int b = bnp / 196, np = bnp % 196;
    int ph = np / 14,  pw = np % 14;
    int c = kk >> 8, rr = kk & 255;
    int i = rr >> 4, j = rr & 15;
    size_t xi = (((size_t)(b*3 + c))*224 + (ph*16 + i))*224 + (pw*16 + j);
    out[idx] = x[xi];
}

// ---------------- assemble h = [cls | patch_emb] + pos, plus bf16 copy ----------------
__global__ __launch_bounds__(256) void assemble_k(const float* __restrict__ pe,
    const bf16_t* __restrict__ cls, const bf16_t* __restrict__ pos,
    float* __restrict__ h, bf16_t* __restrict__ hb){
    int idx = blockIdx.x*256 + threadIdx.x;
    if (idx >= BN*E_) return;
    int e = idx % 768; int bn = idx / 768;
    int b = bn / 197,  n  = bn % 197;
    float v = (n == 0) ? bf2f(cls[e]) : pe[((size_t)b*196 + (n-1))*768 + e];
    float r = v + bf2f(pos[n*768 + e]);
    h[idx]  = r;
    hb[idx] = f2bf(r);
}

// ---------------- qkv split + q/k LayerNorm (D=64); q scaled by 1/8 ----------------
__global__ __launch_bounds__(256) void qkv_split_ln_k(const bf16_t* __restrict__ qkv,
    const bf16_t* __restrict__ qg, const bf16_t* __restrict__ qb,
    const bf16_t* __restrict__ kg, const bf16_t* __restrict__ kb,
    bf16_t* __restrict__ q, bf16_t* __restrict__ k, bf16_t* __restrict__ v){
    int lane = threadIdx.x & 63;
    int item = blockIdx.x*4 + (threadIdx.x >> 6);
    if (item >= BN*NH_) return;
    int bn = item / NH_, h = item % NH_;
    int b = bn / 197,   n = bn % 197;
    size_t src = (size_t)bn*2304 + h*64 + lane;
    size_t dst = (((size_t)(b*NH_ + h))*197 + n)*64 + lane;
    {
        float xv = bf2f(qkv[src]);
        float mu  = wave_rsum(xv) * (1.f/64.f);
        float dd  = xv - mu;
        float var = wave_rsum(dd*dd) * (1.f/64.f);
        q[dst] = f2bf((dd * rsqrtf(var + 1e-5f) * bf2f(qg[lane]) + bf2f(qb[lane])) * 0.125f);
    }
    {
        float xv = bf2f(qkv[src + 768]);
        float mu  = wave_rsum(xv) * (1.f/64.f);
        float dd  = xv - mu;
        float var = wave_rsum(dd*dd) * (1.f/64.f);
        k[dst] = f2bf(dd * rsqrtf(var + 1e-5f) * bf2f(kg[lane]) + bf2f(kb[lane]));
    }
    v[dst] = qkv[src + 1536];
}

// ---------------- V transpose: vn [bh][197][64] -> vt [bh][64][224] (zero-padded) ----------------
__global__ __launch_bounds__(256) void vtrans_k(const bf16_t* __restrict__ vn, bf16_t* __restrict__ vt){
    __shared__ bf16_t tl[32][34];
    const int bh = blockIdx.z;
    const int m0 = blockIdx.x*32, d0 = blockIdx.y*32;
    const int c = threadIdx.x & 31, r = threadIdx.x >> 5;
    const bf16_t* src = vn + (size_t)bh*197*64;
    #pragma unroll
    for (int k = 0; k < 4; ++k){
        int m = m0 + r + 8*k;
        tl[r + 8*k][c] = (m < 197) ? src[(size_t)m*64 + d0 + c] : (bf16_t)0;
    }
    __syncthreads();
    bf16_t* dst = vt + (size_t)bh*64*224;
    #pragma unroll
    for (int k = 0; k < 4; ++k){
        int d = d0 + r + 8*k;
        dst[(size_t)d*224 + m0 + c] = tl[c][r + 8*k];
    }
}

// ---------------- MFMA attention: 1-wave block per (16-query tile, b*h) ----------------
// Q/K fragments straight from global (K rows clamped at 196, masked in softmax).
// Unnormalized P -> bf16 LDS tile [16][232]; PV with V^T (vt) B-frags; O scaled by 1/sum.
// Frag layouts verified by the passing gemm_mfma this session:
//   A-frag lane l = A[l&15][8*(l>>4)+e]; B-frag lane l = B[8*(l>>4)+e][l&15];
//   C/D: col = l&15, row = 4*(l>>4)+reg.
#define PST 232
__global__ __launch_bounds__(64) void attn_mfma_k(const bf16_t* __restrict__ qn,
    const bf16_t* __restrict__ kn, const bf16_t* __restrict__ vt, bf16_t* __restrict__ o){
    __shared__ __align__(16) bf16_t P[16*PST];
    const int lane = threadIdx.x;
    const int i = lane & 15, g = lane >> 4;
    const int bh = blockIdx.y;
    const int b = bh / NH_, h = bh % NH_;
    const int q0 = blockIdx.x * 16;
    const bf16_t* qb = qn + (size_t)bh*197*64;
    const bf16_t* kb = kn + (size_t)bh*197*64;
    const bf16_t* vb = vt + (size_t)bh*64*224;

    // zero the pad cols 208..223 (never rewritten)
    {
        int r = lane >> 2, c0 = 208 + (lane & 3)*4;
        ushort4 z = {0,0,0,0};
        *(ushort4*)&P[r*PST + c0] = z;
    }

    // Q A-frags (rows clamped; out-of-range rows produce dead outputs)
    int qrow = q0 + i; if (qrow > 196) qrow = 196;
    const v8s qa0 = *(const v8s*)(qb + (size_t)qrow*64 + 8*g);
    const v8s qa1 = *(const v8s*)(qb + (size_t)qrow*64 + 32 + 8*g);

    // ---- QK^T: S[q=4g+r][m=16t+i] ----
    v4f s[13];
    #pragma unroll
    for (int t = 0; t < 13; ++t) s[t] = (v4f){0.f,0.f,0.f,0.f};
    #pragma unroll
    for (int t = 0; t < 13; ++t){
        int m = 16*t + i; if (m > 196) m = 196;
        const bf16_t* kr = kb + (size_t)m*64;
        v8s kf0 = *(const v8s*)(kr + 8*g);
        v8s kf1 = *(const v8s*)(kr + 32 + 8*g);
        s[t] = __builtin_amdgcn_mfma_f32_16x16x32_bf16(qa0, kf0, s[t], 0, 0, 0);
        s[t] = __builtin_amdgcn_mfma_f32_16x16x32_bf16(qa1, kf1, s[t], 0, 0, 0);
    }

    // ---- softmax (rows q=4g+r live in 16-lane group g; cols m=16t+i) ----
    float mx[4], sum[4];
    #pragma unroll
    for (int r = 0; r < 4; ++r){
        float m_ = -1e30f;
        #pragma unroll
        for (int t = 0; t < 13; ++t){
            float v = s[t][r];
            if (16*t + i > 196) v = -1e30f;
            m_ = fmaxf(m_, v);
        }
        #pragma unroll
        for (int off = 1; off < 16; off <<= 1) m_ = fmaxf(m_, __shfl_xor(m_, off));
        mx[r] = m_;
        sum[r] = 0.f;
    }
    #pragma unroll
    for (int t = 0; t < 13; ++t){
        #pragma unroll
        for (int r = 0; r < 4; ++r){
            float v = (16*t + i > 196) ? 0.f : __expf(s[t][r] - mx[r]);
            sum[r] += v;
            P[(4*g + r)*PST + 16*t + i] = f2bf(v);
        }
    }
    #pragma unroll
    for (int r = 0; r < 4; ++r){
        float s_ = sum[r];
        #pragma unroll
        for (int off = 1; off < 16; off <<= 1) s_ += __shfl_xor(s_, off);
        sum[r] = 1.f / s_;
    }

    // ---- PV: O[16 q][64 d] = P[16][224] @ V[224][64]  (V via vt[d][m]) ----
    v4f oacc[4];
    #pragma unroll
    for (int j = 0; j < 4; ++j) oacc[j] = (v4f){0.f,0.f,0.f,0.f};
    #pragma unroll
    for (int kc = 0; kc < 7; ++kc){
        v8s pa = *(const v8s*)&P[i*PST + kc*32 + 8*g];
        #pragma unroll
        for (int j = 0; j < 4; ++j){
            v8s vf = *(const v8s*)(vb + (size_t)(16*j + i)*224 + kc*32 + 8*g);
            oacc[j] = __builtin_amdgcn_mfma_f32_16x16x32_bf16(pa, vf, oacc[j], 0, 0, 0);
        }
    }

    // ---- store O (row q=4g+r, col d=16j+i), normalized ----
    #pragma unroll
    for (int r = 0; r < 4; ++r){
        int n = q0 + 4*g + r;
        if (n < 197){
            bf16_t* op = o + ((size_t)(b*197 + n))*768 + h*64;
            #pragma unroll
            for (int j = 0; j < 4; ++j)
                op[16*j + i] = f2bf(oacc[j][r] * sum[r]);
        }
    }
}

// ---------------- legacy VALU attention (fallback path) ----------------
__global__ __launch_bounds__(256) void attn_blk_k(const bf16_t* __restrict__ qn,
    const bf16_t* __restrict__ kn, const bf16_t* __restrict__ vn, bf16_t* __restrict__ o){
    __shared__ unsigned int ktp[32][203];
    __shared__ unsigned int vtp[64][105];
    __shared__ float qly[4][64];
    __shared__ float ply[4][256];
    const int lane = threadIdx.x & 63, wave = threadIdx.x >> 6;
    const int bh = blockIdx.y;
    const int b = bh / NH_, h = bh % NH_;
    const bf16_t* kb = kn + (size_t)bh*197*64;
    const bf16_t* vb = vn + (size_t)bh*197*64;

    for (int m = wave; m < 210; m += 4){
        bf16_t kv = 0, vv = 0;
        if (m < 197){ kv = kb[(size_t)m*64 + lane]; vv = vb[(size_t)m*64 + lane]; }
        if (m < 203)
            ((bf16_t*)ktp)[((size_t)(lane >> 1)*203 + m)*2 + (lane & 1)] = kv;
        ((bf16_t*)vtp)[((size_t)lane*105 + (m >> 1))*2 + (m & 1)] = vv;
    }
    __syncthreads();

    const int n0 = blockIdx.x*16 + wave*4;
    for (int i = 0; i < 4; ++i){
        int n = n0 + i;
        int nn = (n < 197) ? n : 196;
        qly[wave][lane] = bf2f(qn[((size_t)bh*197 + nn)*64 + lane]);
        float s0 = 0.f, s1 = 0.f, s2 = 0.f, s3 = 0.f;
        const int m3 = (lane < 5) ? lane + 192 : 196;
        #pragma unroll 8
        for (int d2 = 0; d2 < 32; ++d2){
            float2 q2 = *(const float2*)&qly[wave][2*d2];
            unsigned int k0 = ktp[d2][lane];
            unsigned int k1 = ktp[d2][lane + 64];
            unsigned int k2 = ktp[d2][lane + 128];
            unsigned int k3 = ktp[d2][m3];
            s0 += q2.x * lo16f(k0) + q2.y * hi16f(k0);
            s1 += q2.x * lo16f(k1) + q2.y * hi16f(k1);
            s2 += q2.x * lo16f(k2) + q2.y * hi16f(k2);
            s3 += q2.x * lo16f(k3) + q2.y * hi16f(k3);
        }
        if (lane >= 5) s3 = -1e30f;
        float mx = wave_rmax(fmaxf(fmaxf(s0, s1), fmaxf(s2, s3)));
        float p0 = expf(s0 - mx), p1 = expf(s1 - mx), p2 = expf(s2 - mx);
        float p3 = (lane < 5) ? expf(s3 - mx) : 0.f;
        float sum = wave_rsum(p0 + p1 + p2 + p3);
        float inv = 1.f / sum;
        ply[wave][lane      ] = p0*inv;
        ply[wave][lane +  64] = p1*inv;
        ply[wave][lane + 128] = p2*inv;
        ply[wave][lane + 192] = p3*inv;
        float acc = 0.f;
        #pragma unroll 4
        for (int m2 = 0; m2 < 99; ++m2){
            float2 p2v = *(const float2*)&ply[wave][2*m2];
            unsigned int vv = vtp[lane][m2];
            acc += p2v.x * lo16f(vv) + p2v.y * hi16f(vv);
        }
        if (n < 197) o[((size_t)(b*197 + n))*768 + h*64 + lane] = f2bf(acc);
    }
}

// ---------------- h[row] += LN(src[row])*g + b ; also writes bf16 copy of h ----------------
__global__ __launch_bounds__(256) void lnadd_k(const float* __restrict__ src,
    const bf16_t* __restrict__ g, const bf16_t* __restrict__ b,
    float* __restrict__ h, bf16_t* __restrict__ hb){
    __shared__ float red[256];
    int t = threadIdx.x;
    size_t row = blockIdx.x;
    const float* p = src + row*768;
    float x0 = p[t], x1 = p[t+256], x2 = p[t+512];
    red[t] = x0 + x1 + x2;
    __syncthreads();
    for (int off = 128; off; off >>= 1){ if (t < off) red[t] += red[t+off]; __syncthreads(); }
    float mean = red[0] * (1.f/768.f);
    __syncthreads();
    float d0 = x0-mean, d1 = x1-mean, d2 = x2-mean;
    red[t] = d0*d0 + d1*d1 + d2*d2;
    __syncthreads();
    for (int off = 128; off; off >>= 1){ if (t < off) red[t] += red[t+off]; __syncthreads(); }
    float inv = rsqrtf(red[0]*(1.f/768.f) + 1e-5f);
    float* hp = h + row*768;
    bf16_t* hq = hb + row*768;
    float r0 = hp[t]     + d0*inv*bf2f(g[t])     + bf2f(b[t]);
    float r1 = hp[t+256] + d1*inv*bf2f(g[t+256]) + bf2f(b[t+256]);
    float r2 = hp[t+512] + d2*inv*bf2f(g[t+512]) + bf2f(b[t+512]);
    hp[t] = r0;     hq[t] = f2bf(r0);
    hp[t+256] = r1; hq[t+256] = f2bf(r1);
    hp[t+512] = r2; hq[t+512] = f2bf(r2);
}

// ---------------- output: h[:,0,:] -> f32 ----------------
__global__ __launch_bounds__(256) void outcopy_k(const float* __restrict__ h, float* __restrict__ out){
    int idx = blockIdx.x*256 + threadIdx.x;
    if (idx >= B_*E_) return;
    int b = idx / 768, e = idx % 768;
    out[idx] = h[(size_t)b*197*768 + e];
}

// ---------------- workspace layout (bytes) ----------------
// [0, 19365888)              h    f32 [6304,768]
// [19365888, 38731776)       t1   f32 [6304,768]  (also attn-out bf16 alias)
// [38731776, ...)            R region (lifetime-overlapped):
//    qkvbuf bf16 [6304,2304] @ R+0 ; patches bf16 @ R+0 ; projout f32 @ R+0
//    vt bf16 [384][64][224]  @ R+0 (11.0MB; qkvbuf dead -> attn; dead before projout)
//    fbuf bf16 [6304,3072]   @ R+0  (extends into dead qn region)
//    qn @ R+29048832, kn @ +9682944, vn/habf @ +9682944
// total = 96,829,440 ; flag @ 96,829,440 ; canonical copies @ 96,829,696
#define OFF_T1   ((size_t)19365888)
#define OFF_R    ((size_t)38731776)
#define OFF_QN   ((size_t)(38731776 + 29048832))        // 67,780,608
#define OFF_KN   ((size_t)(67780608 + 9682944))         // 77,463,552
#define OFF_VN   ((size_t)(77463552 + 9682944))         // 87,146,496
#define OFF_FLAG ((size_t)96829440)
#define OFF_CONV ((size_t)96829696)

extern "C" void kernel_launch(void* const* d_in, const int* in_sizes, int n_in,
                              void* d_out, int out_size, void* d_ws, size_t ws_size,
                              hipStream_t stream) {
    (void)out_size;
    char* wsb = (char*)d_ws;
    float*  h       = (float*)(wsb);
    float*  t1      = (float*)(wsb + OFF_T1);
    bf16_t* abf     = (bf16_t*)(wsb + OFF_T1);          // attn out bf16 (aliases t1)
    bf16_t* qkvbuf  = (bf16_t*)(wsb + OFF_R);
    bf16_t* patches = (bf16_t*)(wsb + OFF_R);
    float*  patchf  = (float*)(wsb + OFF_R);
    float*  projout = (float*)(wsb + OFF_R);
    bf16_t* fbuf    = (bf16_t*)(wsb + OFF_R);
    bf16_t* vtb     = (bf16_t*)(wsb + OFF_R);           // V^T [384][64][224]
    bf16_t* qnb     = (bf16_t*)(wsb + OFF_QN);
    bf16_t* knb     = (bf16_t*)(wsb + OFF_KN);
    bf16_t* vnb     = (bf16_t*)(wsb + OFF_VN);
    bf16_t* habf    = (bf16_t*)(wsb + OFF_VN);          // h bf16 copy (disjoint lifetime vs vn)
    int*    flag    = (int*)(wsb + OFF_FLAG);

    size_t conv_total = 0;
    for (int i = 0; i < n_in; ++i) conv_total += (((size_t)in_sizes[i]*2) + 15) & ~(size_t)15;
    const bool hedge = (ws_size >= OFF_CONV + conv_total);

    const bf16_t* inp[21];
    if (hedge){
        hipMemsetAsync(flag, 0, 4, stream);
        detect_k<<<64, 256, 0, stream>>>((const unsigned short*)d_in[0], in_sizes[0], flag);
        size_t off = 0;
        for (int i = 0; i < n_in && i < 21; ++i){
            bf16_t* dst = (bf16_t*)(wsb + OFF_CONV + off);
            if (i == 5)
                convert_t_k<<<dim3(2304/32, 768/32, 12), 256, 0, stream>>>(d_in[i], dst, 768, 2304, flag);
            else if (i == 11)
                convert_t_k<<<dim3(768/32, 768/32, 12), 256, 0, stream>>>(d_in[i], dst, 768, 768, flag);
            else if (i == 15)
                convert_t_k<<<dim3(3072/32, 768/32, 12), 256, 0, stream>>>(d_in[i], dst, 768, 3072, flag);
            else if (i == 17)
                convert_t_k<<<dim3(768/32, 3072/32, 12), 256, 0, stream>>>(d_in[i], dst, 3072, 768, flag);
            else
                convert_k<<<(in_sizes[i] + 255)/256, 256, 0, stream>>>(d_in[i], dst, in_sizes[i], flag);
            inp[i] = dst;
            off += (((size_t)in_sizes[i]*2) + 15) & ~(size_t)15;
        }
    } else {
        for (int i = 0; i < n_in && i < 21; ++i) inp[i] = (const bf16_t*)d_in[i];
    }

    if (hedge){
        // ---- MFMA pipeline ----
        patchify_bf_k<<<(BNP*E_ + 255)/256, 256, 0, stream>>>(inp[0], patches);
        gemm_mfma<0,0><<<dim3(E_/128, BNP/128), 256, 0, stream>>>(
            patches, inp[1], inp[2], t1, BNP, E_, 768);
        assemble_k<<<(BN*E_ + 255)/256, 256, 0, stream>>>(t1, inp[3], inp[4], h, habf);

        for (int l = 0; l < L_; ++l){
            gemm_mfma<1,0><<<dim3(2304/128, (BN+127)/128), 256, 0, stream>>>(
                habf, inp[5] + (size_t)l*E_*2304, inp[6] + (size_t)l*2304, qkvbuf, BN, 2304, 768);
            qkv_split_ln_k<<<(BN*NH_)/4, 256, 0, stream>>>(
                qkvbuf, inp[7] + l*64, inp[8] + l*64, inp[9] + l*64, inp[10] + l*64,
                qnb, knb, vnb);
            vtrans_k<<<dim3(7, 2, B_*NH_), 256, 0, stream>>>(vnb, vtb);
            attn_mfma_k<<<dim3(13, B_*NH_), 64, 0, stream>>>(qnb, knb, vtb, abf);
            gemm_mfma<0,0><<<dim3(E_/128, (BN+127)/128), 256, 0, stream>>>(
                abf, inp[11] + (size_t)l*E_*E_, inp[12] + (size_t)l*E_, projout, BN, E_, 768);
            lnadd_k<<<BN, 256, 0, stream>>>(projout, inp[13] + l*E_, inp[14] + l*E_, h, habf);
            gemm_mfma<1,1><<<dim3(M_/128, (BN+127)/128), 256, 0, stream>>>(
                habf, inp[15] + (size_t)l*E_*M_, inp[16] + (size_t)l*M_, fbuf, BN, M_, 768);
            gemm_mfma<0,0><<<dim3(E_/128, (BN+127)/128), 256, 0, stream>>>(
                fbuf, inp[17] + (size_t)l*M_*E_, inp[18] + (size_t)l*E_, t1, BN, E_, 3072);
            lnadd_k<<<BN, 256, 0, stream>>>(t1, inp[19] + l*E_, inp[20] + l*E_, h, habf);
        }
    } else {
        // ---- fallback VALU pipeline ----
        dim3 gblk(16, 16);
        patchify_k<<<(BNP*E_ + 255)/256, 256, 0, stream>>>(inp[0], patchf);
        gemm_ab<0,1,0,0><<<dim3(E_/64, BNP/64), gblk, 0, stream>>>(
            patchf, inp[1], inp[2], t1, BNP, E_, 768);
        assemble_k<<<(BN*E_ + 255)/256, 256, 0, stream>>>(t1, inp[3], inp[4], h, habf);
        for (int l = 0; l < L_; ++l){
            gemm_ab<0,0,1,0><<<dim3(2304/64, (BN+63)/64), gblk, 0, stream>>>(
                h, inp[5] + (size_t)l*E_*2304, inp[6] + (size_t)l*2304, qkvbuf, BN, 2304, E_);
            qkv_split_ln_k<<<(BN*NH_)/4, 256, 0, stream>>>(
                qkvbuf, inp[7] + l*64, inp[8] + l*64, inp[9] + l*64, inp[10] + l*64,
                qnb, knb, vnb);
            attn_blk_k<<<dim3(13, B_*NH_), 256, 0, stream>>>(qnb, knb, vnb, abf);
            gemm_ab<1,0,0,0><<<dim3(E_/64, (BN+63)/64), gblk, 0, stream>>>(
                abf, inp[11] + (size_t)l*E_*E_, inp[12] + (size_t)l*E_, projout, BN, E_, E_);
            lnadd_k<<<BN, 256, 0, stream>>>(projout, inp[13] + l*E_, inp[14] + l*E_, h, habf);
            gemm_ab<0,0,1,1><<<dim3(M_/64, (BN+63)/64), gblk, 0, stream>>>(
                h, inp[15] + (size_t)l*E_*M_, inp[16] + (size_t)l*M_, fbuf, BN, M_, E_);
            gemm_ab<1,0,0,0><<<dim3(E_/64, (BN+63)/64), gblk, 0, stream>>>(
                fbuf, inp[17] + (size_t)l*M_*E_, inp[18] + (size_t)l*E_, t1, BN, E_, M_);
            lnadd_k<<<BN, 256, 0, stream>>>(t1, inp[19] + l*E_, inp[20] + l*E_, h, habf);
        }
    }

    outcopy_k<<<(B_*E_ + 255)/256, 256, 0, stream>>>(h, (float*)d_out);
}

// Round 3
// 4893.987 us; speedup vs baseline: 6.0240x; 1.0580x over previous
//
#include <hip/hip_runtime.h>

// ---------------- problem constants ----------------
#define B_    32
#define NTOK  197
#define E_    768
#define NH_   12
#define M_    3072
#define L_    12
#define NPAT  196
#define BN    (B_*NTOK)    // 6304
#define BNP   (B_*NPAT)    // 6272

typedef unsigned short bf16_t;
typedef short v8s __attribute__((ext_vector_type(8)));     // 8 bf16 = 4 VGPR MFMA frag
typedef float v4f __attribute__((ext_vector_type(4)));     // MFMA accumulator
typedef unsigned short u16x8 __attribute__((ext_vector_type(8)));

// ---------------- helpers ----------------
__device__ inline float bf2f(bf16_t u){
    union { unsigned int i; float f; } c; c.i = ((unsigned int)u) << 16; return c.f;
}
__device__ inline bf16_t f2bf(float f){
    union { float f; unsigned int i; } c; c.f = f;
    unsigned int u = c.i;
    u += 0x7FFFu + ((u >> 16) & 1u);   // round-to-nearest-even
    return (bf16_t)(u >> 16);
}
__device__ inline float lo16f(unsigned int u){
    union { unsigned int i; float f; } c; c.i = u << 16; return c.f;
}
__device__ inline float hi16f(unsigned int u){
    union { unsigned int i; float f; } c; c.i = u & 0xFFFF0000u; return c.f;
}
__device__ inline float wave_rsum(float x){
    #pragma unroll
    for (int off = 32; off; off >>= 1) x += __shfl_xor(x, off);
    return x;
}
__device__ inline float wave_rmax(float x){
    #pragma unroll
    for (int off = 32; off; off >>= 1) x = fmaxf(x, __shfl_xor(x, off));
    return x;
}
// async global->LDS, 16B per lane; LDS dest is wave-uniform base + lane*16
__device__ inline void gl2l16(const void* g, void* l){
    typedef __attribute__((address_space(1))) void gv_t;
    typedef __attribute__((address_space(3))) void lv_t;
    __builtin_amdgcn_global_load_lds((gv_t*)(size_t)g, (lv_t*)l, 16, 0, 0);
}

// ---------------- dtype detector ----------------
__global__ __launch_bounds__(256) void detect_k(const unsigned short* __restrict__ x,
                                                int n, int* __restrict__ flag){
    int cnt = 0;
    for (int i = blockIdx.x*256 + threadIdx.x; i < n; i += 256*64)
        { unsigned short u = x[i]; if (((u >> 7) & 0xFFu) == 0xFFu) ++cnt; }
    if (cnt) atomicAdd(flag, cnt);
}

// ---------------- canonicalize to bf16 ----------------
__global__ __launch_bounds__(256) void convert_k(const void* __restrict__ src,
    bf16_t* __restrict__ dst, int n, const int* __restrict__ flag){
    int i = blockIdx.x*256 + threadIdx.x;
    if (i >= n) return;
    if (*flag >= 8) dst[i] = f2bf(((const float*)src)[i]);
    else            dst[i] = ((const bf16_t*)src)[i];
}

// ---------------- transpose-canonicalize: src [L][K][N] -> dst [L][N][K] bf16 ----------------
__global__ __launch_bounds__(256) void convert_t_k(const void* __restrict__ src,
    bf16_t* __restrict__ dst, int K, int N, const int* __restrict__ flag){
    __shared__ float tile[32][33];
    const int l  = blockIdx.z;
    const int n0 = blockIdx.x*32, k0 = blockIdx.y*32;
    const int c  = threadIdx.x & 31, r = threadIdx.x >> 5;
    const bool isf = (*flag >= 8);
    const size_t ibase = (size_t)l*(size_t)K*N;
    #pragma unroll
    for (int i = 0; i < 4; ++i){
        int kk = k0 + r + i*8;
        float v;
        if (isf) v = ((const float*)src)[ibase + (size_t)kk*N + n0 + c];
        else     v = bf2f(((const bf16_t*)src)[ibase + (size_t)kk*N + n0 + c]);
        tile[r + i*8][c] = v;
    }
    __syncthreads();
    #pragma unroll
    for (int i = 0; i < 4; ++i){
        int nn = n0 + r + i*8;
        dst[ibase + (size_t)nn*K + k0 + c] = f2bf(tile[c][r + i*8]);
    }
}

// ---------------- old VALU GEMM (fallback path only) ----------------
template<int AT, int BT, int OT, int ACT>
__global__ __launch_bounds__(256) void gemm_ab(
    const void* __restrict__ A, const bf16_t* __restrict__ Bw,
    const bf16_t* __restrict__ bias, void* __restrict__ C,
    int Mr, int Nc, int K)
{
    __shared__ float As[16][72];
    __shared__ float Bs[16][72];
    const int tx = threadIdx.x, ty = threadIdx.y;
    const int t  = ty*16 + tx;
    const int m0 = blockIdx.y*64, n0 = blockIdx.x*64;
    float acc[4][4] = {};

    for (int k0 = 0; k0 < K; k0 += 16){
        {
            int mm = t >> 2, kk = (t & 3)*4;
            int row = m0 + mm;
            float f0=0.f,f1=0.f,f2=0.f,f3=0.f;
            if (row < Mr){
                if (AT == 0){
                    const float4 v4 = *(const float4*)((const float*)A + (size_t)row*K + k0 + kk);
                    f0=v4.x; f1=v4.y; f2=v4.z; f3=v4.w;
                } else {
                    const ushort4 u4 = *(const ushort4*)((const bf16_t*)A + (size_t)row*K + k0 + kk);
                    f0=bf2f(u4.x); f1=bf2f(u4.y); f2=bf2f(u4.z); f3=bf2f(u4.w);
                }
            }
            As[kk+0][mm]=f0; As[kk+1][mm]=f1; As[kk+2][mm]=f2; As[kk+3][mm]=f3;
        }
        if (BT){
            int nn = t >> 2, kk = (t & 3)*4;
            const ushort4 u4 = *(const ushort4*)(Bw + (size_t)(n0+nn)*K + k0 + kk);
            Bs[kk+0][nn]=bf2f(u4.x); Bs[kk+1][nn]=bf2f(u4.y);
            Bs[kk+2][nn]=bf2f(u4.z); Bs[kk+3][nn]=bf2f(u4.w);
        } else {
            int kk = t >> 4, nn = (t & 15)*4;
            const ushort4 u4 = *(const ushort4*)(Bw + (size_t)(k0+kk)*Nc + n0 + nn);
            Bs[kk][nn+0]=bf2f(u4.x); Bs[kk][nn+1]=bf2f(u4.y);
            Bs[kk][nn+2]=bf2f(u4.z); Bs[kk][nn+3]=bf2f(u4.w);
        }
        __syncthreads();
        #pragma unroll
        for (int kk = 0; kk < 16; ++kk){
            float4 av = *(const float4*)&As[kk][ty*4];
            float4 bv = *(const float4*)&Bs[kk][tx*4];
            float a_[4] = {av.x, av.y, av.z, av.w};
            float b_[4] = {bv.x, bv.y, bv.z, bv.w};
            #pragma unroll
            for (int i=0;i<4;i++)
                #pragma unroll
                for (int j=0;j<4;j++)
                    acc[i][j] += a_[i]*b_[j];
        }
        __syncthreads();
    }
    #pragma unroll
    for (int i=0;i<4;i++){
        int m = m0 + ty*4 + i;
        if (m >= Mr) continue;
        #pragma unroll
        for (int j=0;j<4;j++){
            int n = n0 + tx*4 + j;
            float v = acc[i][j];
            if (bias) v += bf2f(bias[n]);
            if (ACT==1) v = 0.5f*v*(1.f + erff(v*0.70710678118654752f));
            if (OT == 0) ((float*)C)[(size_t)m*Nc + n] = v;
            else         ((bf16_t*)C)[(size_t)m*Nc + n] = f2bf(v);
        }
    }
}

// ---------------- MFMA bf16 GEMM: C[M,N] = A @ Bt^T (+bias, opt GELU) ----------------
// m97 structure: BK=64 (128B LDS rows), global_load_lds width=16 with linear LDS dest
// + inverse-swizzled per-lane global source; reads XOR-swizzled (2-way = free).
// Swizzle: logical (row, kbyte) stored at row*128 + (kbyte ^ ((row&7)<<4)).
// gload_lds instr (wave w, i): LDS rows w*32+i*8+(l>>3), stored chunk l&7,
// so per-lane global chunk = (l&7) ^ (l>>3)  [row&7 == l>>3].
// Requires K%64==0, Nc%128==0; M-edge: source rows clamped, stores guarded.
template<int OT, int ACT>
__global__ __launch_bounds__(256) void gemm_mfma(
    const bf16_t* __restrict__ A, const bf16_t* __restrict__ Bt,
    const bf16_t* __restrict__ bias, void* __restrict__ C,
    int Mr, int Nc, int K)
{
    __shared__ __align__(16) char As[128*128];   // 16 KB
    __shared__ __align__(16) char Bs[128*128];   // 16 KB
    const int t    = threadIdx.x;
    const int lane = t & 63;
    const int wave = t >> 6;
    const int wr = wave >> 1, wc = wave & 1;
    const int m0 = blockIdx.y * 128, n0 = blockIdx.x * 128;

    // ---- staging addresses ----
    const int sub  = lane >> 3;                   // row-within-8 block
    const int kch  = (lane & 7) ^ sub;            // logical 16B chunk (pre-swizzled source)
    const bf16_t* aB[4];
    const bf16_t* bB[4];
    #pragma unroll
    for (int i = 0; i < 4; ++i){
        int ar = m0 + wave*32 + i*8 + sub;
        if (ar >= Mr) ar = Mr - 1;                // clamp; junk outputs never stored
        aB[i] = A  + (size_t)ar * K + kch*8;
        bB[i] = Bt + (size_t)(n0 + wave*32 + i*8 + sub) * K + kch*8;
    }
    char* aL = As + wave*4096;                    // wave-uniform LDS bases
    char* bL = Bs + wave*4096;

    // ---- fragment read offsets ----
    const int fr = lane & 15, fg = lane >> 4;
    const int key = (fr & 7) << 4;
    const int kf0 = (fg*16)      ^ key;           // k-step 0 byte offset within row
    const int kf1 = (64 + fg*16) ^ key;           // k-step 1
    int arb[4], brb[4];
    #pragma unroll
    for (int fi = 0; fi < 4; ++fi){
        arb[fi] = (wr*64 + fi*16 + fr) * 128;
        brb[fi] = (wc*64 + fi*16 + fr) * 128;
    }

    const v4f vzero = {0.f, 0.f, 0.f, 0.f};
    v4f acc[4][4];
    #pragma unroll
    for (int i = 0; i < 4; ++i)
        #pragma unroll
        for (int j = 0; j < 4; ++j)
            acc[i][j] = vzero;

    for (int k0 = 0; k0 < K; k0 += 64){
        #pragma unroll
        for (int i = 0; i < 4; ++i){
            gl2l16(aB[i] + k0, aL + i*1024);
            gl2l16(bB[i] + k0, bL + i*1024);
        }
        __syncthreads();                          // vmcnt(0) drain + barrier: tile ready
        #pragma unroll
        for (int s = 0; s < 2; ++s){
            const int kf = s ? kf1 : kf0;
            v8s af[4], bfv[4];
            #pragma unroll
            for (int fi = 0; fi < 4; ++fi){
                af[fi]  = *(const v8s*)(As + arb[fi] + kf);
                bfv[fi] = *(const v8s*)(Bs + brb[fi] + kf);
            }
            #pragma unroll
            for (int i = 0; i < 4; ++i)
                #pragma unroll
                for (int j = 0; j < 4; ++j)
                    acc[i][j] = __builtin_amdgcn_mfma_f32_16x16x32_bf16(af[i], bfv[j], acc[i][j], 0, 0, 0);
        }
        __syncthreads();                          // all reads done before next overwrite
    }

    // epilogue: C row = 4*(l>>4)+r, col = l&15 within each 16x16 frag
    #pragma unroll
    for (int i = 0; i < 4; ++i){
        #pragma unroll
        for (int r = 0; r < 4; ++r){
            int m = m0 + wr*64 + i*16 + fg*4 + r;
            if (m >= Mr) continue;
            #pragma unroll
            for (int j = 0; j < 4; ++j){
                int n = n0 + wc*64 + j*16 + fr;
                float v = acc[i][j][r];
                if (bias) v += bf2f(bias[n]);
                if (ACT == 1) v = 0.5f*v*(1.f + erff(v*0.70710678118654752f));
                if (OT == 0) ((float*)C)[(size_t)m*Nc + n] = v;
                else         ((bf16_t*)C)[(size_t)m*Nc + n] = f2bf(v);
            }
        }
    }
}

// ---------------- patchify (fallback, f32 out) ----------------
__global__ __launch_bounds__(256) void patchify_k(const bf16_t* __restrict__ x, float* __restrict__ out){
    int idx = blockIdx.x*256 + threadIdx.x;
    if (idx >= BNP*E_) return;
    int kk  = idx % 768;
    int bnp = idx / 768;
    int b = bnp / 196, np = bnp % 196;
    int ph = np / 14,  pw = np % 14;
    int c = kk >> 8, rr = kk & 255;
    int i = rr >> 4, j = rr & 15;
    size_t xi = (((size_t)(b*3 + c))*224 + (ph*16 + i))*224 + (pw*16 + j);
    out[idx] = bf2f(x[xi]);
}

// ---------------- patchify bf16 out (hedge path) ----------------
__global__ __launch_bounds__(256) void patchify_bf_k(const bf16_t* __restrict__ x, bf16_t* __restrict__ out){
    int idx = blockIdx.x*256 + threadIdx.x;
    if (idx >= BNP*E_) return;
    int kk  = idx % 768;
    int bnp = idx / 768;
    int b = bnp / 196, np = bnp % 196;
    int ph = np / 14,  pw = np % 14;
    int c = kk >> 8, rr = kk & 255;
    int i = rr >> 4, j = rr & 15;
    size_t xi = (((size_t)(b*3 + c))*224 + (ph*16 + i))*224 + (pw*16 + j);
    out[idx] = x[xi];
}

// ---------------- assemble h = [cls | patch_emb] + pos, plus bf16 copy ----------------
__global__ __launch_bounds__(256) void assemble_k(const float* __restrict__ pe,
    const bf16_t* __restrict__ cls, const bf16_t* __restrict__ pos,
    float* __restrict__ h, bf16_t* __restrict__ hb){
    int idx = blockIdx.x*256 + threadIdx.x;
    if (idx >= BN*E_) return;
    int e = idx % 768; int bn = idx / 768;
    int b = bn / 197,  n  = bn % 197;
    float v = (n == 0) ? bf2f(cls[e]) : pe[((size_t)b*196 + (n-1))*768 + e];
    float r = v + bf2f(pos[n*768 + e]);
    h[idx]  = r;
    hb[idx] = f2bf(r);
}

// ---------------- qkv split + q/k LayerNorm (D=64); q scaled by 1/8 ----------------
__global__ __launch_bounds__(256) void qkv_split_ln_k(const bf16_t* __restrict__ qkv,
    const bf16_t* __restrict__ qg, const bf16_t* __restrict__ qb,
    const bf16_t* __restrict__ kg, const bf16_t* __restrict__ kb,
    bf16_t* __restrict__ q, bf16_t* __restrict__ k, bf16_t* __restrict__ v){
    int lane = threadIdx.x & 63;
    int item = blockIdx.x*4 + (threadIdx.x >> 6);
    if (item >= BN*NH_) return;
    int bn = item / NH_, h = item % NH_;
    int b = bn / 197,   n = bn % 197;
    size_t src = (size_t)bn*2304 + h*64 + lane;
    size_t dst = (((size_t)(b*NH_ + h))*197 + n)*64 + lane;
    {
        float xv = bf2f(qkv[src]);
        float mu  = wave_rsum(xv) * (1.f/64.f);
        float dd  = xv - mu;
        float var = wave_rsum(dd*dd) * (1.f/64.f);
        q[dst] = f2bf((dd * rsqrtf(var + 1e-5f) * bf2f(qg[lane]) + bf2f(qb[lane])) * 0.125f);
    }
    {
        float xv = bf2f(qkv[src + 768]);
        float mu  = wave_rsum(xv) * (1.f/64.f);
        float dd  = xv - mu;
        float var = wave_rsum(dd*dd) * (1.f/64.f);
        k[dst] = f2bf(dd * rsqrtf(var + 1e-5f) * bf2f(kg[lane]) + bf2f(kb[lane]));
    }
    v[dst] = qkv[src + 1536];
}

// ---------------- V transpose: vn [bh][197][64] -> vt [bh][64][224] (zero-padded) ----------------
__global__ __launch_bounds__(256) void vtrans_k(const bf16_t* __restrict__ vn, bf16_t* __restrict__ vt){
    __shared__ bf16_t tl[32][34];
    const int bh = blockIdx.z;
    const int m0 = blockIdx.x*32, d0 = blockIdx.y*32;
    const int c = threadIdx.x & 31, r = threadIdx.x >> 5;
    const bf16_t* src = vn + (size_t)bh*197*64;
    #pragma unroll
    for (int k = 0; k < 4; ++k){
        int m = m0 + r + 8*k;
        tl[r + 8*k][c] = (m < 197) ? src[(size_t)m*64 + d0 + c] : (bf16_t)0;
    }
    __syncthreads();
    bf16_t* dst = vt + (size_t)bh*64*224;
    #pragma unroll
    for (int k = 0; k < 4; ++k){
        int d = d0 + r + 8*k;
        dst[(size_t)d*224 + m0 + c] = tl[c][r + 8*k];
    }
}

// ---------------- MFMA attention: 1-wave block per (16-query tile, b*h) ----------------
#define PST 232
__global__ __launch_bounds__(64) void attn_mfma_k(const bf16_t* __restrict__ qn,
    const bf16_t* __restrict__ kn, const bf16_t* __restrict__ vt, bf16_t* __restrict__ o){
    __shared__ __align__(16) bf16_t P[16*PST];
    const int lane = threadIdx.x;
    const int i = lane & 15, g = lane >> 4;
    const int bh = blockIdx.y;
    const int b = bh / NH_, h = bh % NH_;
    const int q0 = blockIdx.x * 16;
    const bf16_t* qb = qn + (size_t)bh*197*64;
    const bf16_t* kb = kn + (size_t)bh*197*64;
    const bf16_t* vb = vt + (size_t)bh*64*224;

    {
        int r = lane >> 2, c0 = 208 + (lane & 3)*4;
        ushort4 z = {0,0,0,0};
        *(ushort4*)&P[r*PST + c0] = z;
    }

    int qrow = q0 + i; if (qrow > 196) qrow = 196;
    const v8s qa0 = *(const v8s*)(qb + (size_t)qrow*64 + 8*g);
    const v8s qa1 = *(const v8s*)(qb + (size_t)qrow*64 + 32 + 8*g);

    v4f s[13];
    #pragma unroll
    for (int t = 0; t < 13; ++t) s[t] = (v4f){0.f,0.f,0.f,0.f};
    #pragma unroll
    for (int t = 0; t < 13; ++t){
        int m = 16*t + i; if (m > 196) m = 196;
        const bf16_t* kr = kb + (size_t)m*64;
        v8s kf0 = *(const v8s*)(kr + 8*g);
        v8s kf1 = *(const v8s*)(kr + 32 + 8*g);
        s[t] = __builtin_amdgcn_mfma_f32_16x16x32_bf16(qa0, kf0, s[t], 0, 0, 0);
        s[t] = __builtin_amdgcn_mfma_f32_16x16x32_bf16(qa1, kf1, s[t], 0, 0, 0);
    }

    float mx[4], sum[4];
    #pragma unroll
    for (int r = 0; r < 4; ++r){
        float m_ = -1e30f;
        #pragma unroll
        for (int t = 0; t < 13; ++t){
            float v = s[t][r];
            if (16*t + i > 196) v = -1e30f;
            m_ = fmaxf(m_, v);
        }
        #pragma unroll
        for (int off = 1; off < 16; off <<= 1) m_ = fmaxf(m_, __shfl_xor(m_, off));
        mx[r] = m_;
        sum[r] = 0.f;
    }
    #pragma unroll
    for (int t = 0; t < 13; ++t){
        #pragma unroll
        for (int r = 0; r < 4; ++r){
            float v = (16*t + i > 196) ? 0.f : __expf(s[t][r] - mx[r]);
            sum[r] += v;
            P[(4*g + r)*PST + 16*t + i] = f2bf(v);
        }
    }
    #pragma unroll
    for (int r = 0; r < 4; ++r){
        float s_ = sum[r];
        #pragma unroll
        for (int off = 1; off < 16; off <<= 1) s_ += __shfl_xor(s_, off);
        sum[r] = 1.f / s_;
    }

    v4f oacc[4];
    #pragma unroll
    for (int j = 0; j < 4; ++j) oacc[j] = (v4f){0.f,0.f,0.f,0.f};
    #pragma unroll
    for (int kc = 0; kc < 7; ++kc){
        v8s pa = *(const v8s*)&P[i*PST + kc*32 + 8*g];
        #pragma unroll
        for (int j = 0; j < 4; ++j){
            v8s vf = *(const v8s*)(vb + (size_t)(16*j + i)*224 + kc*32 + 8*g);
            oacc[j] = __builtin_amdgcn_mfma_f32_16x16x32_bf16(pa, vf, oacc[j], 0, 0, 0);
        }
    }

    #pragma unroll
    for (int r = 0; r < 4; ++r){
        int n = q0 + 4*g + r;
        if (n < 197){
            bf16_t* op = o + ((size_t)(b*197 + n))*768 + h*64;
            #pragma unroll
            for (int j = 0; j < 4; ++j)
                op[16*j + i] = f2bf(oacc[j][r] * sum[r]);
        }
    }
}

// ---------------- legacy VALU attention (fallback path) ----------------
__global__ __launch_bounds__(256) void attn_blk_k(const bf16_t* __restrict__ qn,
    const bf16_t* __restrict__ kn, const bf16_t* __restrict__ vn, bf16_t* __restrict__ o){
    __shared__ unsigned int ktp[32][203];
    __shared__ unsigned int vtp[64][105];
    __shared__ float qly[4][64];
    __shared__ float ply[4][256];
    const int lane = threadIdx.x & 63, wave = threadIdx.x >> 6;
    const int bh = blockIdx.y;
    const int b = bh / NH_, h = bh % NH_;
    const bf16_t* kb = kn + (size_t)bh*197*64;
    const bf16_t* vb = vn + (size_t)bh*197*64;

    for (int m = wave; m < 210; m += 4){
        bf16_t kv = 0, vv = 0;
        if (m < 197){ kv = kb[(size_t)m*64 + lane]; vv = vb[(size_t)m*64 + lane]; }
        if (m < 203)
            ((bf16_t*)ktp)[((size_t)(lane >> 1)*203 + m)*2 + (lane & 1)] = kv;
        ((bf16_t*)vtp)[((size_t)lane*105 + (m >> 1))*2 + (m & 1)] = vv;
    }
    __syncthreads();

    const int n0 = blockIdx.x*16 + wave*4;
    for (int i = 0; i < 4; ++i){
        int n = n0 + i;
        int nn = (n < 197) ? n : 196;
        qly[wave][lane] = bf2f(qn[((size_t)bh*197 + nn)*64 + lane]);
        float s0 = 0.f, s1 = 0.f, s2 = 0.f, s3 = 0.f;
        const int m3 = (lane < 5) ? lane + 192 : 196;
        #pragma unroll 8
        for (int d2 = 0; d2 < 32; ++d2){
            float2 q2 = *(const float2*)&qly[wave][2*d2];
            unsigned int k0 = ktp[d2][lane];
            unsigned int k1 = ktp[d2][lane + 64];
            unsigned int k2 = ktp[d2][lane + 128];
            unsigned int k3 = ktp[d2][m3];
            s0 += q2.x * lo16f(k0) + q2.y * hi16f(k0);
            s1 += q2.x * lo16f(k1) + q2.y * hi16f(k1);
            s2 += q2.x * lo16f(k2) + q2.y * hi16f(k2);
            s3 += q2.x * lo16f(k3) + q2.y * hi16f(k3);
        }
        if (lane >= 5) s3 = -1e30f;
        float mx = wave_rmax(fmaxf(fmaxf(s0, s1), fmaxf(s2, s3)));
        float p0 = expf(s0 - mx), p1 = expf(s1 - mx), p2 = expf(s2 - mx);
        float p3 = (lane < 5) ? expf(s3 - mx) : 0.f;
        float sum = wave_rsum(p0 + p1 + p2 + p3);
        float inv = 1.f / sum;
        ply[wave][lane      ] = p0*inv;
        ply[wave][lane +  64] = p1*inv;
        ply[wave][lane + 128] = p2*inv;
        ply[wave][lane + 192] = p3*inv;
        float acc = 0.f;
        #pragma unroll 4
        for (int m2 = 0; m2 < 99; ++m2){
            float2 p2v = *(const float2*)&ply[wave][2*m2];
            unsigned int vv = vtp[lane][m2];
            acc += p2v.x * lo16f(vv) + p2v.y * hi16f(vv);
        }
        if (n < 197) o[((size_t)(b*197 + n))*768 + h*64 + lane] = f2bf(acc);
    }
}

// ---------------- h[row] += LN(src[row])*g + b ; also writes bf16 copy of h ----------------
__global__ __launch_bounds__(256) void lnadd_k(const float* __restrict__ src,
    const bf16_t* __restrict__ g, const bf16_t* __restrict__ b,
    float* __restrict__ h, bf16_t* __restrict__ hb){
    __shared__ float red[256];
    int t = threadIdx.x;
    size_t row = blockIdx.x;
    const float* p = src + row*768;
    float x0 = p[t], x1 = p[t+256], x2 = p[t+512];
    red[t] = x0 + x1 + x2;
    __syncthreads();
    for (int off = 128; off; off >>= 1){ if (t < off) red[t] += red[t+off]; __syncthreads(); }
    float mean = red[0] * (1.f/768.f);
    __syncthreads();
    float d0 = x0-mean, d1 = x1-mean, d2 = x2-mean;
    red[t] = d0*d0 + d1*d1 + d2*d2;
    __syncthreads();
    for (int off = 128; off; off >>= 1){ if (t < off) red[t] += red[t+off]; __syncthreads(); }
    float inv = rsqrtf(red[0]*(1.f/768.f) + 1e-5f);
    float* hp = h + row*768;
    bf16_t* hq = hb + row*768;
    float r0 = hp[t]     + d0*inv*bf2f(g[t])     + bf2f(b[t]);
    float r1 = hp[t+256] + d1*inv*bf2f(g[t+256]) + bf2f(b[t+256]);
    float r2 = hp[t+512] + d2*inv*bf2f(g[t+512]) + bf2f(b[t+512]);
    hp[t] = r0;     hq[t] = f2bf(r0);
    hp[t+256] = r1; hq[t+256] = f2bf(r1);
    hp[t+512] = r2; hq[t+512] = f2bf(r2);
}

// ---------------- output: h[:,0,:] -> f32 ----------------
__global__ __launch_bounds__(256) void outcopy_k(const float* __restrict__ h, float* __restrict__ out){
    int idx = blockIdx.x*256 + threadIdx.x;
    if (idx >= B_*E_) return;
    int b = idx / 768, e = idx % 768;
    out[idx] = h[(size_t)b*197*768 + e];
}

// ---------------- workspace layout (bytes) ----------------
#define OFF_T1   ((size_t)19365888)
#define OFF_R    ((size_t)38731776)
#define OFF_QN   ((size_t)(38731776 + 29048832))        // 67,780,608
#define OFF_KN   ((size_t)(67780608 + 9682944))         // 77,463,552
#define OFF_VN   ((size_t)(77463552 + 9682944))         // 87,146,496
#define OFF_FLAG ((size_t)96829440)
#define OFF_CONV ((size_t)96829696)

extern "C" void kernel_launch(void* const* d_in, const int* in_sizes, int n_in,
                              void* d_out, int out_size, void* d_ws, size_t ws_size,
                              hipStream_t stream) {
    (void)out_size;
    char* wsb = (char*)d_ws;
    float*  h       = (float*)(wsb);
    float*  t1      = (float*)(wsb + OFF_T1);
    bf16_t* abf     = (bf16_t*)(wsb + OFF_T1);          // attn out bf16 (aliases t1)
    bf16_t* qkvbuf  = (bf16_t*)(wsb + OFF_R);
    bf16_t* patches = (bf16_t*)(wsb + OFF_R);
    float*  patchf  = (float*)(wsb + OFF_R);
    float*  projout = (float*)(wsb + OFF_R);
    bf16_t* fbuf    = (bf16_t*)(wsb + OFF_R);
    bf16_t* vtb     = (bf16_t*)(wsb + OFF_R);           // V^T [384][64][224]
    bf16_t* qnb     = (bf16_t*)(wsb + OFF_QN);
    bf16_t* knb     = (bf16_t*)(wsb + OFF_KN);
    bf16_t* vnb     = (bf16_t*)(wsb + OFF_VN);
    bf16_t* habf    = (bf16_t*)(wsb + OFF_VN);          // h bf16 copy (disjoint lifetime vs vn)
    int*    flag    = (int*)(wsb + OFF_FLAG);

    size_t conv_total = 0;
    for (int i = 0; i < n_in; ++i) conv_total += (((size_t)in_sizes[i]*2) + 15) & ~(size_t)15;
    const bool hedge = (ws_size >= OFF_CONV + conv_total);

    const bf16_t* inp[21];
    if (hedge){
        hipMemsetAsync(flag, 0, 4, stream);
        detect_k<<<64, 256, 0, stream>>>((const unsigned short*)d_in[0], in_sizes[0], flag);
        size_t off = 0;
        for (int i = 0; i < n_in && i < 21; ++i){
            bf16_t* dst = (bf16_t*)(wsb + OFF_CONV + off);
            if (i == 5)
                convert_t_k<<<dim3(2304/32, 768/32, 12), 256, 0, stream>>>(d_in[i], dst, 768, 2304, flag);
            else if (i == 11)
                convert_t_k<<<dim3(768/32, 768/32, 12), 256, 0, stream>>>(d_in[i], dst, 768, 768, flag);
            else if (i == 15)
                convert_t_k<<<dim3(3072/32, 768/32, 12), 256, 0, stream>>>(d_in[i], dst, 768, 3072, flag);
            else if (i == 17)
                convert_t_k<<<dim3(768/32, 3072/32, 12), 256, 0, stream>>>(d_in[i], dst, 3072, 768, flag);
            else
                convert_k<<<(in_sizes[i] + 255)/256, 256, 0, stream>>>(d_in[i], dst, in_sizes[i], flag);
            inp[i] = dst;
            off += (((size_t)in_sizes[i]*2) + 15) & ~(size_t)15;
        }
    } else {
        for (int i = 0; i < n_in && i < 21; ++i) inp[i] = (const bf16_t*)d_in[i];
    }

    if (hedge){
        // ---- MFMA pipeline ----
        patchify_bf_k<<<(BNP*E_ + 255)/256, 256, 0, stream>>>(inp[0], patches);
        gemm_mfma<0,0><<<dim3(E_/128, BNP/128), 256, 0, stream>>>(
            patches, inp[1], inp[2], t1, BNP, E_, 768);
        assemble_k<<<(BN*E_ + 255)/256, 256, 0, stream>>>(t1, inp[3], inp[4], h, habf);

        for (int l = 0; l < L_; ++l){
            gemm_mfma<1,0><<<dim3(2304/128, (BN+127)/128), 256, 0, stream>>>(
                habf, inp[5] + (size_t)l*E_*2304, inp[6] + (size_t)l*2304, qkvbuf, BN, 2304, 768);
            qkv_split_ln_k<<<(BN*NH_)/4, 256, 0, stream>>>(
                qkvbuf, inp[7] + l*64, inp[8] + l*64, inp[9] + l*64, inp[10] + l*64,
                qnb, knb, vnb);
            vtrans_k<<<dim3(7, 2, B_*NH_), 256, 0, stream>>>(vnb, vtb);
            attn_mfma_k<<<dim3(13, B_*NH_), 64, 0, stream>>>(qnb, knb, vtb, abf);
            gemm_mfma<0,0><<<dim3(E_/128, (BN+127)/128), 256, 0, stream>>>(
                abf, inp[11] + (size_t)l*E_*E_, inp[12] + (size_t)l*E_, projout, BN, E_, 768);
            lnadd_k<<<BN, 256, 0, stream>>>(projout, inp[13] + l*E_, inp[14] + l*E_, h, habf);
            gemm_mfma<1,1><<<dim3(M_/128, (BN+127)/128), 256, 0, stream>>>(
                habf, inp[15] + (size_t)l*E_*M_, inp[16] + (size_t)l*M_, fbuf, BN, M_, 768);
            gemm_mfma<0,0><<<dim3(E_/128, (BN+127)/128), 256, 0, stream>>>(
                fbuf, inp[17] + (size_t)l*M_*E_, inp[18] + (size_t)l*E_, t1, BN, E_, 3072);
            lnadd_k<<<BN, 256, 0, stream>>>(t1, inp[19] + l*E_, inp[20] + l*E_, h, habf);
        }
    } else {
        // ---- fallback VALU pipeline ----
        dim3 gblk(16, 16);
        patchify_k<<<(BNP*E_ + 255)/256, 256, 0, stream>>>(inp[0], patchf);
        gemm_ab<0,1,0,0><<<dim3(E_/64, BNP/64), gblk, 0, stream>>>(
            patchf, inp[1], inp[2], t1, BNP, E_, 768);
        assemble_k<<<(BN*E_ + 255)/256, 256, 0, stream>>>(t1, inp[3], inp[4], h, habf);
        for (int l = 0; l < L_; ++l){
            gemm_ab<0,0,1,0><<<dim3(2304/64, (BN+63)/64), gblk, 0, stream>>>(
                h, inp[5] + (size_t)l*E_*2304, inp[6] + (size_t)l*2304, qkvbuf, BN, 2304, E_);
            qkv_split_ln_k<<<(BN*NH_)/4, 256, 0, stream>>>(
                qkvbuf, inp[7] + l*64, inp[8] + l*64, inp[9] + l*64, inp[10] + l*64,
                qnb, knb, vnb);
            attn_blk_k<<<dim3(13, B_*NH_), 256, 0, stream>>>(qnb, knb, vnb, abf);
            gemm_ab<1,0,0,0><<<dim3(E_/64, (BN+63)/64), gblk, 0, stream>>>(
                abf, inp[11] + (size_t)l*E_*E_, inp[12] + (size_t)l*E_, projout, BN, E_, E_);
            lnadd_k<<<BN, 256, 0, stream>>>(projout, inp[13] + l*E_, inp[14] + l*E_, h, habf);
            gemm_ab<0,0,1,1><<<dim3(M_/64, (BN+63)/64), gblk, 0, stream>>>(
                h, inp[15] + (size_t)l*E_*M_, inp[16] + (size_t)l*M_, fbuf, BN, M_, E_);
            gemm_ab<1,0,0,0><<<dim3(E_/64, (BN+63)/64), gblk, 0, stream>>>(
                fbuf, inp[17] + (size_t)l*M_*E_, inp[18] + (size_t)l*E_, t1, BN, E_, M_);
            lnadd_k<<<BN, 256, 0, stream>>>(t1, inp[19] + l*E_, inp[20] + l*E_, h, habf);
        }
    }

    outcopy_k<<<(B_*E_ + 255)/256, 256, 0, stream>>>(h, (float*)d_out);
}